// Round 6
// baseline (45994.031 us; speedup 1.0000x reference)
//
#include <hip/hip_runtime.h>
#include <hip/hip_bf16.h>
#include <math.h>

#define BATCH 128
#define QD 88
#define HDIM 512
#define ZDIM 1280
#define GDIM 2048
#define DYNC 1024          // dynamic cols after folding static h_target block
#define NPAST 10
#define NTRANS 29
#define NSTEPS (NPAST + NTRANS)
#define OUTD 95
#define POSE_ELEMS (BATCH * 30 * 91)

typedef float f32x4 __attribute__((ext_vector_type(4)));
typedef unsigned int u32x4 __attribute__((ext_vector_type(4)));
typedef unsigned int u32x2 __attribute__((ext_vector_type(2)));

__device__ __forceinline__ float sig_(float x) { return 1.0f / (1.0f + expf(-x)); }
__device__ __forceinline__ float bflo_(unsigned u) { return __uint_as_float(u << 16); }
__device__ __forceinline__ float bfhi_(unsigned u) { return __uint_as_float(u & 0xffff0000u); }
__device__ __forceinline__ unsigned bfrne_(float f) {
    return (__float_as_uint(f) + 0x7fffu + ((__float_as_uint(f) >> 16) & 1u)) >> 16;
}
__device__ __forceinline__ void dot8_(const u32x4 wv, const float4 za, const float4 zb,
                                      float& d) {
    d = fmaf(bflo_(wv.x), za.x, d); d = fmaf(bfhi_(wv.x), za.y, d);
    d = fmaf(bflo_(wv.y), za.z, d); d = fmaf(bfhi_(wv.y), za.w, d);
    d = fmaf(bflo_(wv.z), zb.x, d); d = fmaf(bfhi_(wv.z), zb.y, d);
    d = fmaf(bflo_(wv.w), zb.z, d); d = fmaf(bfhi_(wv.w), zb.w, d);
}
__device__ __forceinline__ void dot4_(const uint4 wv, const float4 zv, float& d) {
    const float4 f = *(const float4*)&wv;
    d = fmaf(f.x, zv.x, d); d = fmaf(f.y, zv.y, d);
    d = fmaf(f.z, zv.z, d); d = fmaf(f.w, zv.w, d);
}
__device__ __forceinline__ void fma4_(float4& acc, float x, const float4 w) {
    acc.x = fmaf(x, w.x, acc.x); acc.y = fmaf(x, w.y, acc.y);
    acc.z = fmaf(x, w.z, acc.z); acc.w = fmaf(x, w.w, acc.w);
}

// ---------------- zero the per-(step,sample) arrival counters ----------------
__global__ void __launch_bounds__(256)
zerok(int* __restrict__ cnt, int n)
{
    const int i = blockIdx.x * 256 + threadIdx.x;
    if (i < n) cnt[i] = 0;
}

// ---- conversion + static-column fold: Wd bf16[b][2048][1024], g0 = bias + W[:,512:768].h_tgt ----
// grid 4096 = 128 x 32 row-chunks; block 256 = 4 waves; wave: 16 rows
__global__ void __launch_bounds__(256)
conv2k(const float* __restrict__ pw, const float* __restrict__ pred_bias,
       const float* __restrict__ z_ws, unsigned short* __restrict__ Wd,
       float* __restrict__ g0_ws)
{
    const int b = blockIdx.x >> 5, rc = blockIdx.x & 31;
    const int wave = threadIdx.x >> 6, lane = threadIdx.x & 63;
    const float4 ht4 = *(const float4*)(z_ws + b * ZDIM + 512 + 4 * lane);
    const float* src = pw + (size_t)b * GDIM * ZDIM;
    char* dstB = (char*)(Wd + (size_t)b * GDIM * DYNC);

    for (int i = 0; i < 16; ++i) {
        const int row = rc * 64 + wave * 16 + i;
        const float* rs = src + (size_t)row * ZDIM + 4 * lane;
        char* rd = dstB + (size_t)row * (DYNC * 2) + 8 * lane;
        // cols: [0,512) dyn | [512,768) static dot | [768,1280) dyn
        #pragma unroll
        for (int k = 0; k < 2; ++k) {
            const f32x4 f = __builtin_nontemporal_load((const f32x4*)(rs + k * 256));
            u32x2 o; o.x = bfrne_(f.x) | (bfrne_(f.y) << 16);
            o.y = bfrne_(f.z) | (bfrne_(f.w) << 16);
            __builtin_nontemporal_store(o, (u32x2*)(rd + k * 512));
        }
        const f32x4 fs = __builtin_nontemporal_load((const f32x4*)(rs + 512));
        float sp = fs.x * ht4.x + fs.y * ht4.y + fs.z * ht4.z + fs.w * ht4.w;
        #pragma unroll
        for (int k = 0; k < 2; ++k) {
            const f32x4 f = __builtin_nontemporal_load((const f32x4*)(rs + 768 + k * 256));
            u32x2 o; o.x = bfrne_(f.x) | (bfrne_(f.y) << 16);
            o.y = bfrne_(f.z) | (bfrne_(f.w) << 16);
            __builtin_nontemporal_store(o, (u32x2*)(rd + 1024 + k * 512));
        }
        #pragma unroll
        for (int m = 32; m >= 1; m >>= 1) sp += __shfl_xor(sp, m, 64);
        if (lane == 0) g0_ws[b * GDIM + row] = sp + pred_bias[b * GDIM + row];
    }
}

// ---------------- init: state=0, h_target, step-0 encoders ----------------
__global__ void __launch_bounds__(512)
initk(const float* __restrict__ past_root_vel, const float* __restrict__ past_quats,
      const float* __restrict__ past_root_offset, const float* __restrict__ past_quat_offset,
      const float* __restrict__ past_contacts, const float* __restrict__ target_quats,
      const float* __restrict__ init_root_pos,
      const float* __restrict__ se_w1, const float* __restrict__ se_b1,
      const float* __restrict__ se_w2, const float* __restrict__ se_b2,
      const float* __restrict__ oe_w1, const float* __restrict__ oe_b1,
      const float* __restrict__ oe_w2, const float* __restrict__ oe_b2,
      const float* __restrict__ te_w1, const float* __restrict__ te_b1,
      const float* __restrict__ te_w2, const float* __restrict__ te_b2,
      float* __restrict__ z_ws, float* __restrict__ c_ws, float* __restrict__ car_ws)
{
    const int b = blockIdx.x, t = threadIdx.x;
    __shared__ float tq[QD], bufA[512], bufB[512], sv[95], ov[91];

    if (t < 192) car_ws[b * 192 + t] = (t < 3) ? init_root_pos[b * 3 + t] : 0.f;
    c_ws[b * HDIM + t] = 0.f;
    z_ws[b * ZDIM + 768 + t] = 0.f;
    if (t < QD) tq[t] = target_quats[b * QD + t];
    if (t < 4)  sv[t] = past_contacts[b * NPAST * 4 + t];
    if (t < QD) { sv[4 + t] = past_quats[b * NPAST * QD + t];
                  ov[3 + t] = past_quat_offset[b * NPAST * QD + t]; }
    if (t < 3)  { sv[92 + t] = past_root_vel[b * NPAST * 3 + t];
                  ov[t]      = past_root_offset[b * NPAST * 3 + t]; }
    __syncthreads();
    {
        float a = te_b1[t];
        #pragma unroll 8
        for (int i = 0; i < QD; ++i) a = fmaf(tq[i], te_w1[i * 512 + t], a);
        bufA[t] = fmaxf(a, 0.f);
    }
    __syncthreads();
    if (t < 256) {
        float a = te_b2[t];
        #pragma unroll 8
        for (int i = 0; i < 512; ++i) a = fmaf(bufA[i], te_w2[i * 256 + t], a);
        z_ws[b * ZDIM + 512 + t] = fmaxf(a, 0.f);
    }
    __syncthreads();
    {
        float aS = se_b1[t], aO = oe_b1[t];
        #pragma unroll 8
        for (int i = 0; i < 91; ++i) { aS = fmaf(sv[i], se_w1[i * 512 + t], aS);
                                       aO = fmaf(ov[i], oe_w1[i * 512 + t], aO); }
        #pragma unroll
        for (int i = 91; i < 95; ++i) aS = fmaf(sv[i], se_w1[i * 512 + t], aS);
        bufA[t] = fmaxf(aS, 0.f);
        bufB[t] = fmaxf(aO, 0.f);
    }
    __syncthreads();
    if (t < 256) {
        float a = se_b2[t];
        #pragma unroll 8
        for (int i = 0; i < 512; ++i) a = fmaf(bufA[i], se_w2[i * 256 + t], a);
        z_ws[b * ZDIM + t] = fmaxf(a, 0.f);
    } else {
        const int j = t - 256;
        float a = oe_b2[j];
        #pragma unroll 8
        for (int i = 0; i < 512; ++i) a = fmaf(bufB[i], oe_w2[i * 256 + j], a);
        z_ws[b * ZDIM + 256 + j] = fmaxf(a, 0.f);
    }
}

// ---------------- fused per-step kernel: GEMV (all blocks) + step tail (chunk-0) ----------------
// grid 4096 = 128 samples x 32 chunks; block 256 = 4 waves; wave: 16 rows (8 pairs)
__global__ void __launch_bounds__(256, 4)
fusedk(const unsigned short* __restrict__ Wd, const float* __restrict__ g0_ws,
       const float* __restrict__ past_root_vel, const float* __restrict__ past_quats,
       const float* __restrict__ past_root_offset, const float* __restrict__ past_quat_offset,
       const float* __restrict__ past_contacts, const float* __restrict__ target_root_pos,
       const float* __restrict__ target_quats,
       const float* __restrict__ se_w1, const float* __restrict__ se_b1,
       const float* __restrict__ se_w2, const float* __restrict__ se_b2,
       const float* __restrict__ oe_w1, const float* __restrict__ oe_b1,
       const float* __restrict__ oe_w2, const float* __restrict__ oe_b2,
       const float* __restrict__ de_w1, const float* __restrict__ de_b1,
       const float* __restrict__ de_w2, const float* __restrict__ de_b2,
       const float* __restrict__ de_w3, const float* __restrict__ de_b3,
       float* __restrict__ out, float* __restrict__ z_ws, float* __restrict__ g_ws,
       float* __restrict__ c_ws, float* __restrict__ car_ws, int* __restrict__ cnt, int s)
{
    const int b = blockIdx.x >> 5, chunk = blockIdx.x & 31;
    const int t = threadIdx.x;
    const int wave = t >> 6, lane = t & 63;
    const int row0 = chunk * 64 + wave * 16;
    const float* zb = z_ws + b * ZDIM;
    const int l8 = lane * 8;
    // two z fragments: P = z[0:512) slice, Q = z[768:1280) slice
    const float4 pA = *(const float4*)(zb + l8),       pB = *(const float4*)(zb + l8 + 4);
    const float4 qA = *(const float4*)(zb + 768 + l8), qB = *(const float4*)(zb + 768 + l8 + 4);
    const float g0v = (lane < 16) ? g0_ws[b * GDIM + row0 + lane] : 0.f;
    const char* wb = (const char*)Wd + (size_t)b * GDIM * DYNC * 2;

    #define ISSUE(p, B) { const char* a_ = wb + (size_t)(row0 + 2 * (p)) * (DYNC * 2) + lane * 16; \
        B[0] = __builtin_nontemporal_load((const u32x4*)(a_)); \
        B[1] = __builtin_nontemporal_load((const u32x4*)(a_ + 1024)); \
        B[2] = __builtin_nontemporal_load((const u32x4*)(a_ + 2048)); \
        B[3] = __builtin_nontemporal_load((const u32x4*)(a_ + 3072)); }

    u32x4 bufa[4], bufb[4];
    ISSUE(0, bufa);
    #pragma unroll
    for (int p = 0; p < 8; ++p) {
        u32x4* cur = (p & 1) ? bufb : bufa;
        u32x4* nxt = (p & 1) ? bufa : bufb;
        if (p < 7) ISSUE(p + 1, nxt);
        float accA = 0.f, accB = 0.f;
        dot8_(cur[0], pA, pB, accA); dot8_(cur[1], qA, qB, accA);
        dot8_(cur[2], pA, pB, accB); dot8_(cur[3], qA, qB, accB);
        float s0 = accA + __shfl_xor(accA, 32);
        float s1 = accB + __shfl_xor(accB, 32);
        float u = (lane < 32) ? s0 : s1;
        #pragma unroll
        for (int m = 16; m >= 1; m >>= 1) u += __shfl_xor(u, m);
        const float badd = __shfl(g0v, 2 * p + ((lane >= 32) ? 1 : 0), 64);
        if (lane == 0)       g_ws[b * GDIM + row0 + 2 * p]     = u + badd;
        else if (lane == 32) g_ws[b * GDIM + row0 + 2 * p + 1] = u + badd;
    }
    #undef ISSUE

    // release: make our gate rows visible, then arrive
    __threadfence();
    __syncthreads();
    int* mycnt = cnt + s * BATCH + b;
    if (t == 0) atomicAdd(mycnt, 1);
    if (chunk != 0) return;

    // chunk-0: wait for all 32 chunks of this sample
    if (t == 0) {
        while (__hip_atomic_load(mycnt, __ATOMIC_ACQUIRE, __HIP_MEMORY_SCOPE_AGENT) < 32)
            __builtin_amdgcn_s_sleep(8);
        __threadfence();
    }
    __syncthreads();

    // ======== step tail (256 threads) ========
    __shared__ float4 part4[256];
    __shared__ __align__(16) float h2s[HDIM], bufA[512], bufB[512], d2[256];
    __shared__ float outv[OUTD], nq[QD], sv[95], ov[91], carryL[192], tq[QD], trp[3];
    __shared__ float rvn[3], globn[3], contn[4];

    if (t < 192) carryL[t] = car_ws[b * 192 + t];
    if (t < QD) tq[t] = target_quats[b * QD + t];
    if (t < 3)  trp[t] = target_root_pos[b * 3 + t];

    // LSTM (gates already have bias+static folded)
    {
        const float* g = g_ws + b * GDIM;
        #pragma unroll
        for (int i = 0; i < 2; ++i) {
            const int j = t + 256 * i;
            const float ig = g[j], fg = g[512 + j], gg = g[1024 + j], og = g[1536 + j];
            const float c2 = sig_(fg) * c_ws[b * HDIM + j] + sig_(ig) * tanhf(gg);
            c_ws[b * HDIM + j] = c2;
            const float h2 = sig_(og) * tanhf(c2);
            h2s[j] = h2;
            z_ws[b * ZDIM + 768 + j] = h2;
        }
    }
    __syncthreads();

    // decoder L1: 512 -> 512.  128 float4 out-groups x 2 slices of 256
    {
        const int c = t & 127, sl = t >> 7;
        float4 acc = {0.f, 0.f, 0.f, 0.f};
        const float* w = de_w1 + (size_t)(sl * 256) * 512 + 4 * c;
        #pragma unroll 8
        for (int k = 0; k < 256; ++k)
            fma4_(acc, h2s[sl * 256 + k], *(const float4*)(w + (size_t)k * 512));
        part4[t] = acc;
    }
    __syncthreads();
    if (t < 128) {
        const float4 a = part4[t], b2 = part4[128 + t];
        const float4 bb = *(const float4*)(de_b1 + 4 * t);
        float4 r; r.x = fmaxf(a.x + b2.x + bb.x, 0.f); r.y = fmaxf(a.y + b2.y + bb.y, 0.f);
        r.z = fmaxf(a.z + b2.z + bb.z, 0.f); r.w = fmaxf(a.w + b2.w + bb.w, 0.f);
        *(float4*)&bufA[4 * t] = r;
    }
    __syncthreads();

    // decoder L2: 512 -> 256.  64 out-groups x 4 slices of 128
    {
        const int c = t & 63, sl = t >> 6;
        float4 acc = {0.f, 0.f, 0.f, 0.f};
        const float* w = de_w2 + (size_t)(sl * 128) * 256 + 4 * c;
        #pragma unroll 8
        for (int k = 0; k < 128; ++k)
            fma4_(acc, bufA[sl * 128 + k], *(const float4*)(w + (size_t)k * 256));
        part4[t] = acc;
    }
    __syncthreads();
    if (t < 64) {
        float4 v = part4[t];
        #pragma unroll
        for (int sl = 1; sl < 4; ++sl) { const float4 p = part4[sl * 64 + t];
            v.x += p.x; v.y += p.y; v.z += p.z; v.w += p.w; }
        const float4 bb = *(const float4*)(de_b2 + 4 * t);
        float4 r; r.x = fmaxf(v.x + bb.x, 0.f); r.y = fmaxf(v.y + bb.y, 0.f);
        r.z = fmaxf(v.z + bb.z, 0.f); r.w = fmaxf(v.w + bb.w, 0.f);
        *(float4*)&d2[4 * t] = r;
    }
    __syncthreads();

    // decoder L3: 256 -> 95
    if (t < OUTD) {
        float acc = de_b3[t];
        #pragma unroll 16
        for (int i = 0; i < 256; ++i) acc = fmaf(d2[i], de_w3[i * OUTD + t], acc);
        outv[t] = acc;
    }
    __syncthreads();

    // ---- state update ----
    const bool pastS = (s < NPAST);
    if (t < QD) {
        const float qin = pastS ? past_quats[(b * NPAST + s) * QD + t] : carryL[10 + t];
        nq[t] = outv[t] + qin;
    }
    __syncthreads();
    if (t < 22) {
        const float a = nq[4 * t], b2 = nq[4 * t + 1], c3 = nq[4 * t + 2], d4 = nq[4 * t + 3];
        const float inv = 1.f / fmaxf(sqrtf(a * a + b2 * b2 + c3 * c3 + d4 * d4), 1e-12f);
        nq[4 * t] = a * inv; nq[4 * t + 1] = b2 * inv; nq[4 * t + 2] = c3 * inv; nq[4 * t + 3] = d4 * inv;
    }
    if (t < 3) {
        const float rin = pastS ? past_root_vel[(b * NPAST + s) * 3 + t] : carryL[3 + t];
        const float nrv = outv[88 + t] + rin;
        const float g = carryL[t] + (pastS ? rin : nrv);
        rvn[t] = nrv; globn[t] = g;
    }
    if (t < 4) contn[t] = sig_(outv[91 + t]);
    __syncthreads();

    // carry out + frame outputs
    if (t < 3) { car_ws[b * 192 + t] = globn[t]; car_ws[b * 192 + 3 + t] = rvn[t];
                 car_ws[b * 192 + 186 + t] = globn[t] - trp[t]; }
    if (t < 4) car_ws[b * 192 + 6 + t] = contn[t];
    if (t < QD) { car_ws[b * 192 + 10 + t] = nq[t]; car_ws[b * 192 + 98 + t] = nq[t] - tq[t]; }
    if (s == NPAST - 1) {
        const size_t pb = (size_t)b * 30 * 91;
        if (t < 3)  out[pb + t] = rvn[t];
        if (t < QD) out[pb + 3 + t] = nq[t];
        if (t < 4)  out[POSE_ELEMS + (size_t)b * 30 * 4 + t] = contn[t];
    } else if (!pastS) {
        const int k = s - NPAST + 1;
        const size_t pb = ((size_t)b * 30 + k) * 91;
        if (t < 3)  out[pb + t] = globn[t];
        if (t < QD) out[pb + 3 + t] = nq[t];
        if (t < 4)  out[POSE_ELEMS + ((size_t)b * 30 + k) * 4 + t] = contn[t];
    }
    if (s == NSTEPS - 1) return;

    // ---- encoders for step s+1 ----
    const int nx = s + 1;
    if (nx < NPAST) {
        if (t < 4)  sv[t] = past_contacts[(b * NPAST + nx) * 4 + t];
        if (t < QD) { sv[4 + t] = past_quats[(b * NPAST + nx) * QD + t];
                      ov[3 + t] = past_quat_offset[(b * NPAST + nx) * QD + t]; }
        if (t < 3)  { sv[92 + t] = past_root_vel[(b * NPAST + nx) * 3 + t];
                      ov[t]      = past_root_offset[(b * NPAST + nx) * 3 + t]; }
    } else {
        if (t < 4)  sv[t] = contn[t];
        if (t < QD) { sv[4 + t] = nq[t]; ov[3 + t] = nq[t] - tq[t]; }
        if (t < 3)  { sv[92 + t] = rvn[t]; ov[t] = globn[t] - trp[t]; }
    }
    __syncthreads();

    // enc L1: se (95 in) threads 0..127, oe (91 in) threads 128..255; 128 float4 groups each
    {
        const int enc = t >> 7, c = t & 127;
        const float* inp = enc ? ov : sv;
        const float* w1  = enc ? oe_w1 : se_w1;
        const float* b1  = enc ? oe_b1 : se_b1;
        const int nin = enc ? 91 : 95;
        float4 acc = {0.f, 0.f, 0.f, 0.f};
        for (int i = 0; i < nin; ++i)
            fma4_(acc, inp[i], *(const float4*)(w1 + (size_t)i * 512 + 4 * c));
        const float4 bb = *(const float4*)(b1 + 4 * c);
        float4 r; r.x = fmaxf(acc.x + bb.x, 0.f); r.y = fmaxf(acc.y + bb.y, 0.f);
        r.z = fmaxf(acc.z + bb.z, 0.f); r.w = fmaxf(acc.w + bb.w, 0.f);
        if (enc) *(float4*)&bufB[4 * c] = r; else *(float4*)&bufA[4 * c] = r;
    }
    __syncthreads();

    // enc L2: 512 -> 256 each; 64 groups x 2 slices of 256, per half-block
    {
        const int enc = t >> 7, tt = t & 127;
        const int c = tt & 63, sl = tt >> 6;
        const float* inp = enc ? bufB : bufA;
        const float* w2  = enc ? oe_w2 : se_w2;
        float4 acc = {0.f, 0.f, 0.f, 0.f};
        const float* w = w2 + (size_t)(sl * 256) * 256 + 4 * c;
        #pragma unroll 8
        for (int k = 0; k < 256; ++k)
            fma4_(acc, inp[sl * 256 + k], *(const float4*)(w + (size_t)k * 256));
        part4[t] = acc;
    }
    __syncthreads();
    if (t < 64) {
        const float4 a = part4[t], b2 = part4[64 + t];
        const float4 bb = *(const float4*)(se_b2 + 4 * t);
        float4 r; r.x = fmaxf(a.x + b2.x + bb.x, 0.f); r.y = fmaxf(a.y + b2.y + bb.y, 0.f);
        r.z = fmaxf(a.z + b2.z + bb.z, 0.f); r.w = fmaxf(a.w + b2.w + bb.w, 0.f);
        *(float4*)(z_ws + b * ZDIM + 4 * t) = r;
    } else if (t < 128) {
        const int c = t - 64;
        const float4 a = part4[128 + c], b2 = part4[192 + c];
        const float4 bb = *(const float4*)(oe_b2 + 4 * c);
        float4 r; r.x = fmaxf(a.x + b2.x + bb.x, 0.f); r.y = fmaxf(a.y + b2.y + bb.y, 0.f);
        r.z = fmaxf(a.z + b2.z + bb.z, 0.f); r.w = fmaxf(a.w + b2.w + bb.w, 0.f);
        *(float4*)(z_ws + b * ZDIM + 256 + 4 * c) = r;
    }
}

// ================= fp32 fallback path (ws too small): R4 kernels =================
__global__ void __launch_bounds__(256)
matvec_f32(const float* __restrict__ W, const float* __restrict__ z_ws,
           const float* __restrict__ pred_bias, float* __restrict__ g_ws)
{
    const int b = blockIdx.x >> 5, chunk = blockIdx.x & 31;
    const int wave = threadIdx.x >> 6, lane = threadIdx.x & 63;
    const int row0 = chunk * 64 + wave * 16;
    const float* zb = z_ws + b * ZDIM;
    const float biasv = (lane < 16) ? pred_bias[b * GDIM + row0 + lane] : 0.f;
    const int l4 = lane * 4;
    const float4 z0 = *(const float4*)(zb + l4);
    const float4 z1 = *(const float4*)(zb + 256 + l4);
    const float4 z2 = *(const float4*)(zb + 512 + l4);
    const float4 z3 = *(const float4*)(zb + 768 + l4);
    const float4 z4 = *(const float4*)(zb + 1024 + l4);
    const char* wb = (const char*)W + (size_t)b * GDIM * ZDIM * 4;

    #define ISSUE(p, B) { const char* a_ = wb + (size_t)(row0 + 2 * (p)) * (ZDIM * 4) + lane * 16; \
        _Pragma("unroll") for (int i = 0; i < 10; ++i) B[i] = *(const uint4*)(a_ + i * 1024); }

    uint4 bufa[10], bufb[10];
    ISSUE(0, bufa);
    #pragma unroll
    for (int p = 0; p < 8; ++p) {
        uint4* cur = (p & 1) ? bufb : bufa;
        uint4* nxt = (p & 1) ? bufa : bufb;
        if (p < 7) ISSUE(p + 1, nxt);
        float accA = 0.f, accB = 0.f;
        dot4_(cur[0], z0, accA); dot4_(cur[1], z1, accA); dot4_(cur[2], z2, accA);
        dot4_(cur[3], z3, accA); dot4_(cur[4], z4, accA);
        dot4_(cur[5], z0, accB); dot4_(cur[6], z1, accB); dot4_(cur[7], z2, accB);
        dot4_(cur[8], z3, accB); dot4_(cur[9], z4, accB);
        float s0 = accA + __shfl_xor(accA, 32);
        float s1 = accB + __shfl_xor(accB, 32);
        float u = (lane < 32) ? s0 : s1;
        #pragma unroll
        for (int m = 16; m >= 1; m >>= 1) u += __shfl_xor(u, m);
        const float badd = __shfl(biasv, 2 * p + ((lane >= 32) ? 1 : 0), 64);
        if (lane == 0)       g_ws[b * GDIM + row0 + 2 * p]     = u + badd;
        else if (lane == 32) g_ws[b * GDIM + row0 + 2 * p + 1] = u + badd;
    }
    #undef ISSUE
}

__global__ void __launch_bounds__(512)
stepk(const float* __restrict__ past_root_vel, const float* __restrict__ past_quats,
      const float* __restrict__ past_root_offset, const float* __restrict__ past_quat_offset,
      const float* __restrict__ past_contacts, const float* __restrict__ target_root_pos,
      const float* __restrict__ target_quats,
      const float* __restrict__ se_w1, const float* __restrict__ se_b1,
      const float* __restrict__ se_w2, const float* __restrict__ se_b2,
      const float* __restrict__ oe_w1, const float* __restrict__ oe_b1,
      const float* __restrict__ oe_w2, const float* __restrict__ oe_b2,
      const float* __restrict__ de_w1, const float* __restrict__ de_b1,
      const float* __restrict__ de_w2, const float* __restrict__ de_b2,
      const float* __restrict__ de_w3, const float* __restrict__ de_b3,
      float* __restrict__ out, float* __restrict__ z_ws, const float* __restrict__ g_ws,
      float* __restrict__ c_ws, float* __restrict__ car_ws, int s)
{
    const int b = blockIdx.x, t = threadIdx.x;
    __shared__ float4 part4[512];
    __shared__ __align__(16) float h2s[HDIM], bufA[512], bufB[512], d2[256];
    __shared__ float outv[OUTD], nq[QD], sv[95], ov[91], carryL[192], tq[QD], trp[3];
    __shared__ float rvn[3], globn[3], contn[4];

    if (t < 192) carryL[t] = car_ws[b * 192 + t];
    if (t < QD) tq[t] = target_quats[b * QD + t];
    if (t < 3)  trp[t] = target_root_pos[b * 3 + t];

    {
        const float* g = g_ws + b * GDIM;
        const float ig = g[t], fg = g[512 + t], gg = g[1024 + t], og = g[1536 + t];
        const float c2 = sig_(fg) * c_ws[b * HDIM + t] + sig_(ig) * tanhf(gg);
        c_ws[b * HDIM + t] = c2;
        const float h2 = sig_(og) * tanhf(c2);
        h2s[t] = h2;
        z_ws[b * ZDIM + 768 + t] = h2;
    }
    __syncthreads();
    {
        const int c = t & 127, s4 = t >> 7;
        float4 acc = {0.f, 0.f, 0.f, 0.f};
        const float* w = de_w1 + (size_t)(s4 * 128) * 512 + 4 * c;
        #pragma unroll 8
        for (int k = 0; k < 128; ++k)
            fma4_(acc, h2s[s4 * 128 + k], *(const float4*)(w + (size_t)k * 512));
        part4[t] = acc;
    }
    __syncthreads();
    if (t < 128) {
        float4 v = part4[t];
        #pragma unroll
        for (int s4 = 1; s4 < 4; ++s4) { const float4 p = part4[s4 * 128 + t];
            v.x += p.x; v.y += p.y; v.z += p.z; v.w += p.w; }
        const float4 bb = *(const float4*)(de_b1 + 4 * t);
        float4 r; r.x = fmaxf(v.x + bb.x, 0.f); r.y = fmaxf(v.y + bb.y, 0.f);
        r.z = fmaxf(v.z + bb.z, 0.f); r.w = fmaxf(v.w + bb.w, 0.f);
        *(float4*)&bufA[4 * t] = r;
    }
    __syncthreads();
    {
        const int c = t & 63, s8 = t >> 6;
        float4 acc = {0.f, 0.f, 0.f, 0.f};
        const float* w = de_w2 + (size_t)(s8 * 64) * 256 + 4 * c;
        #pragma unroll 8
        for (int k = 0; k < 64; ++k)
            fma4_(acc, bufA[s8 * 64 + k], *(const float4*)(w + (size_t)k * 256));
        part4[t] = acc;
    }
    __syncthreads();
    if (t < 64) {
        float4 v = part4[t];
        #pragma unroll
        for (int s8 = 1; s8 < 8; ++s8) { const float4 p = part4[s8 * 64 + t];
            v.x += p.x; v.y += p.y; v.z += p.z; v.w += p.w; }
        const float4 bb = *(const float4*)(de_b2 + 4 * t);
        float4 r; r.x = fmaxf(v.x + bb.x, 0.f); r.y = fmaxf(v.y + bb.y, 0.f);
        r.z = fmaxf(v.z + bb.z, 0.f); r.w = fmaxf(v.w + bb.w, 0.f);
        *(float4*)&d2[4 * t] = r;
    }
    __syncthreads();
    if (t < OUTD) {
        float acc = de_b3[t];
        #pragma unroll 16
        for (int i = 0; i < 256; ++i) acc = fmaf(d2[i], de_w3[i * OUTD + t], acc);
        outv[t] = acc;
    }
    __syncthreads();

    const bool pastS = (s < NPAST);
    if (t < QD) {
        const float qin = pastS ? past_quats[(b * NPAST + s) * QD + t] : carryL[10 + t];
        nq[t] = outv[t] + qin;
    }
    __syncthreads();
    if (t < 22) {
        const float a = nq[4 * t], b2 = nq[4 * t + 1], c3 = nq[4 * t + 2], d4 = nq[4 * t + 3];
        const float inv = 1.f / fmaxf(sqrtf(a * a + b2 * b2 + c3 * c3 + d4 * d4), 1e-12f);
        nq[4 * t] = a * inv; nq[4 * t + 1] = b2 * inv; nq[4 * t + 2] = c3 * inv; nq[4 * t + 3] = d4 * inv;
    }
    if (t < 3) {
        const float rin = pastS ? past_root_vel[(b * NPAST + s) * 3 + t] : carryL[3 + t];
        const float nrv = outv[88 + t] + rin;
        const float g = carryL[t] + (pastS ? rin : nrv);
        rvn[t] = nrv; globn[t] = g;
    }
    if (t < 4) contn[t] = sig_(outv[91 + t]);
    __syncthreads();

    if (t < 3) { car_ws[b * 192 + t] = globn[t]; car_ws[b * 192 + 3 + t] = rvn[t];
                 car_ws[b * 192 + 186 + t] = globn[t] - trp[t]; }
    if (t < 4) car_ws[b * 192 + 6 + t] = contn[t];
    if (t < QD) { car_ws[b * 192 + 10 + t] = nq[t]; car_ws[b * 192 + 98 + t] = nq[t] - tq[t]; }
    if (s == NPAST - 1) {
        const size_t pb = (size_t)b * 30 * 91;
        if (t < 3)  out[pb + t] = rvn[t];
        if (t < QD) out[pb + 3 + t] = nq[t];
        if (t < 4)  out[POSE_ELEMS + (size_t)b * 30 * 4 + t] = contn[t];
    } else if (!pastS) {
        const int k = s - NPAST + 1;
        const size_t pb = ((size_t)b * 30 + k) * 91;
        if (t < 3)  out[pb + t] = globn[t];
        if (t < QD) out[pb + 3 + t] = nq[t];
        if (t < 4)  out[POSE_ELEMS + ((size_t)b * 30 + k) * 4 + t] = contn[t];
    }
    if (s == NSTEPS - 1) return;

    const int nx = s + 1;
    if (nx < NPAST) {
        if (t < 4)  sv[t] = past_contacts[(b * NPAST + nx) * 4 + t];
        if (t < QD) { sv[4 + t] = past_quats[(b * NPAST + nx) * QD + t];
                      ov[3 + t] = past_quat_offset[(b * NPAST + nx) * QD + t]; }
        if (t < 3)  { sv[92 + t] = past_root_vel[(b * NPAST + nx) * 3 + t];
                      ov[t]      = past_root_offset[(b * NPAST + nx) * 3 + t]; }
    } else {
        if (t < 4)  sv[t] = contn[t];
        if (t < QD) { sv[4 + t] = nq[t]; ov[3 + t] = nq[t] - tq[t]; }
        if (t < 3)  { sv[92 + t] = rvn[t]; ov[t] = globn[t] - trp[t]; }
    }
    __syncthreads();
    {
        const int tt = t & 255, enc = t >> 8;
        const int c = tt & 127, sl = tt >> 7;
        const float* inp = enc ? ov : sv;
        const float* w1  = enc ? oe_w1 : se_w1;
        const int nin  = enc ? 91 : 95;
        const int half = enc ? 46 : 48;
        const int i0 = sl * half;
        const int iend = (i0 + half < nin) ? (i0 + half) : nin;
        float4 acc = {0.f, 0.f, 0.f, 0.f};
        #pragma unroll 8
        for (int k = 0; k < 48; ++k) {
            const int i = i0 + k;
            if (i < iend) fma4_(acc, inp[i], *(const float4*)(w1 + (size_t)i * 512 + 4 * c));
        }
        part4[enc * 256 + tt] = acc;
    }
    __syncthreads();
    if (t < 128) {
        const float4 a = part4[t], b2 = part4[128 + t];
        const float4 bb = *(const float4*)(se_b1 + 4 * t);
        float4 r; r.x = fmaxf(a.x + b2.x + bb.x, 0.f); r.y = fmaxf(a.y + b2.y + bb.y, 0.f);
        r.z = fmaxf(a.z + b2.z + bb.z, 0.f); r.w = fmaxf(a.w + b2.w + bb.w, 0.f);
        *(float4*)&bufA[4 * t] = r;
    } else if (t < 256) {
        const int c = t - 128;
        const float4 a = part4[256 + c], b2 = part4[384 + c];
        const float4 bb = *(const float4*)(oe_b1 + 4 * c);
        float4 r; r.x = fmaxf(a.x + b2.x + bb.x, 0.f); r.y = fmaxf(a.y + b2.y + bb.y, 0.f);
        r.z = fmaxf(a.z + b2.z + bb.z, 0.f); r.w = fmaxf(a.w + b2.w + bb.w, 0.f);
        *(float4*)&bufB[4 * c] = r;
    }
    __syncthreads();
    {
        const int tt = t & 255, enc = t >> 8;
        const int c = tt & 63, sl = tt >> 6;
        const float* inp = enc ? bufB : bufA;
        const float* w2  = enc ? oe_w2 : se_w2;
        float4 acc = {0.f, 0.f, 0.f, 0.f};
        const float* w = w2 + (size_t)(sl * 128) * 256 + 4 * c;
        #pragma unroll 8
        for (int k = 0; k < 128; ++k)
            fma4_(acc, inp[sl * 128 + k], *(const float4*)(w + (size_t)k * 256));
        part4[enc * 256 + tt] = acc;
    }
    __syncthreads();
    if (t < 64) {
        float4 v = part4[t];
        #pragma unroll
        for (int sl = 1; sl < 4; ++sl) { const float4 p = part4[sl * 64 + t];
            v.x += p.x; v.y += p.y; v.z += p.z; v.w += p.w; }
        const float4 bb = *(const float4*)(se_b2 + 4 * t);
        float4 r; r.x = fmaxf(v.x + bb.x, 0.f); r.y = fmaxf(v.y + bb.y, 0.f);
        r.z = fmaxf(v.z + bb.z, 0.f); r.w = fmaxf(v.w + bb.w, 0.f);
        *(float4*)(z_ws + b * ZDIM + 4 * t) = r;
    } else if (t < 128) {
        const int c = t - 64;
        float4 v = part4[256 + c];
        #pragma unroll
        for (int sl = 1; sl < 4; ++sl) { const float4 p = part4[256 + sl * 64 + c];
            v.x += p.x; v.y += p.y; v.z += p.z; v.w += p.w; }
        const float4 bb = *(const float4*)(oe_b2 + 4 * c);
        float4 r; r.x = fmaxf(v.x + bb.x, 0.f); r.y = fmaxf(v.y + bb.y, 0.f);
        r.z = fmaxf(v.z + bb.z, 0.f); r.w = fmaxf(v.w + bb.w, 0.f);
        *(float4*)(z_ws + b * ZDIM + 256 + 4 * c) = r;
    }
}

extern "C" void kernel_launch(void* const* d_in, const int* in_sizes, int n_in,
                              void* d_out, int out_size, void* d_ws, size_t ws_size,
                              hipStream_t stream) {
    const float* prv = (const float*)d_in[0];
    const float* pq  = (const float*)d_in[1];
    const float* pro = (const float*)d_in[2];
    const float* pqo = (const float*)d_in[3];
    const float* pc  = (const float*)d_in[4];
    const float* trp = (const float*)d_in[5];
    const float* tq  = (const float*)d_in[6];
    const float* irp = (const float*)d_in[7];
    const float* pw  = (const float*)d_in[8];
    const float* pb  = (const float*)d_in[9];
    const float* se_w1 = (const float*)d_in[10]; const float* se_b1 = (const float*)d_in[11];
    const float* se_w2 = (const float*)d_in[12]; const float* se_b2 = (const float*)d_in[13];
    const float* oe_w1 = (const float*)d_in[14]; const float* oe_b1 = (const float*)d_in[15];
    const float* oe_w2 = (const float*)d_in[16]; const float* oe_b2 = (const float*)d_in[17];
    const float* te_w1 = (const float*)d_in[18]; const float* te_b1 = (const float*)d_in[19];
    const float* te_w2 = (const float*)d_in[20]; const float* te_b2 = (const float*)d_in[21];
    const float* de_w1 = (const float*)d_in[22]; const float* de_b1 = (const float*)d_in[23];
    const float* de_w2 = (const float*)d_in[24]; const float* de_b2 = (const float*)d_in[25];
    const float* de_w3 = (const float*)d_in[26]; const float* de_b3 = (const float*)d_in[27];
    float* outp = (float*)d_out;

    const size_t WB2  = (size_t)BATCH * GDIM * DYNC * 2;   // bf16 dynamic weights
    const size_t NCNT = (size_t)NSTEPS * BATCH;
    const size_t AUXB = (size_t)BATCH * (GDIM + ZDIM + GDIM + HDIM + 192) * 4 + NCNT * 4;
    const bool bf = ws_size >= WB2 + AUXB;

    char* base = (char*)d_ws;
    float* g0_ws; float* z_ws; float* g_ws; float* c_ws; float* car_ws; int* cnt;
    if (bf) {
        g0_ws  = (float*)(base + WB2);
        z_ws   = g0_ws + (size_t)BATCH * GDIM;
    } else {
        g0_ws  = nullptr;
        z_ws   = (float*)base;
    }
    g_ws   = z_ws + (size_t)BATCH * ZDIM;
    c_ws   = g_ws + (size_t)BATCH * GDIM;
    car_ws = c_ws + (size_t)BATCH * HDIM;
    cnt    = (int*)(car_ws + (size_t)BATCH * 192);

    initk<<<dim3(BATCH), dim3(512), 0, stream>>>(prv, pq, pro, pqo, pc, tq, irp,
        se_w1, se_b1, se_w2, se_b2, oe_w1, oe_b1, oe_w2, oe_b2,
        te_w1, te_b1, te_w2, te_b2, z_ws, c_ws, car_ws);

    if (bf) {
        zerok<<<dim3((NSTEPS * BATCH + 255) / 256), dim3(256), 0, stream>>>(cnt, NSTEPS * BATCH);
        conv2k<<<dim3(BATCH * 32), dim3(256), 0, stream>>>(pw, pb, z_ws,
            (unsigned short*)d_ws, g0_ws);
        for (int s = 0; s < NSTEPS; ++s) {
            fusedk<<<dim3(BATCH * 32), dim3(256), 0, stream>>>(
                (const unsigned short*)d_ws, g0_ws, prv, pq, pro, pqo, pc, trp, tq,
                se_w1, se_b1, se_w2, se_b2, oe_w1, oe_b1, oe_w2, oe_b2,
                de_w1, de_b1, de_w2, de_b2, de_w3, de_b3,
                outp, z_ws, g_ws, c_ws, car_ws, cnt, s);
        }
    } else {
        for (int s = 0; s < NSTEPS; ++s) {
            matvec_f32<<<dim3(BATCH * 32), dim3(256), 0, stream>>>(pw, z_ws, pb, g_ws);
            stepk<<<dim3(BATCH), dim3(512), 0, stream>>>(prv, pq, pro, pqo, pc, trp, tq,
                se_w1, se_b1, se_w2, se_b2, oe_w1, oe_b1, oe_w2, oe_b2,
                de_w1, de_b1, de_w2, de_b2, de_w3, de_b3,
                outp, z_ws, g_ws, c_ws, car_ws, s);
        }
    }
}

// Round 7
// 5422.963 us; speedup vs baseline: 8.4813x; 8.4813x over previous
//
#include <hip/hip_runtime.h>
#include <hip/hip_bf16.h>
#include <math.h>

#define BATCH 128
#define QD 88
#define HDIM 512
#define ZDIM 1280
#define GDIM 2048
#define DYNC 1024          // dynamic cols after folding static h_target block
#define NPAST 10
#define NTRANS 29
#define NSTEPS (NPAST + NTRANS)
#define OUTD 95
#define POSE_ELEMS (BATCH * 30 * 91)

typedef float f32x4 __attribute__((ext_vector_type(4)));
typedef unsigned int u32x4 __attribute__((ext_vector_type(4)));
typedef unsigned int u32x2 __attribute__((ext_vector_type(2)));

__device__ __forceinline__ float sig_(float x) { return 1.0f / (1.0f + expf(-x)); }
__device__ __forceinline__ float bflo_(unsigned u) { return __uint_as_float(u << 16); }
__device__ __forceinline__ float bfhi_(unsigned u) { return __uint_as_float(u & 0xffff0000u); }
__device__ __forceinline__ unsigned bfrne_(float f) {
    return (__float_as_uint(f) + 0x7fffu + ((__float_as_uint(f) >> 16) & 1u)) >> 16;
}
__device__ __forceinline__ void dot8_(const u32x4 wv, const float4 za, const float4 zb,
                                      float& d) {
    d = fmaf(bflo_(wv.x), za.x, d); d = fmaf(bfhi_(wv.x), za.y, d);
    d = fmaf(bflo_(wv.y), za.z, d); d = fmaf(bfhi_(wv.y), za.w, d);
    d = fmaf(bflo_(wv.z), zb.x, d); d = fmaf(bfhi_(wv.z), zb.y, d);
    d = fmaf(bflo_(wv.w), zb.z, d); d = fmaf(bfhi_(wv.w), zb.w, d);
}
__device__ __forceinline__ void dot4_(const uint4 wv, const float4 zv, float& d) {
    const float4 f = *(const float4*)&wv;
    d = fmaf(f.x, zv.x, d); d = fmaf(f.y, zv.y, d);
    d = fmaf(f.z, zv.z, d); d = fmaf(f.w, zv.w, d);
}
__device__ __forceinline__ void fma4_(float4& acc, float x, const float4 w) {
    acc.x = fmaf(x, w.x, acc.x); acc.y = fmaf(x, w.y, acc.y);
    acc.z = fmaf(x, w.z, acc.z); acc.w = fmaf(x, w.w, acc.w);
}

// ---- conversion + static-column fold: Wd bf16[b][2048][1024], g0 = bias + W[:,512:768].h_tgt ----
// grid 4096 = 128 x 32 row-chunks; block 256 = 4 waves; wave: 16 rows
__global__ void __launch_bounds__(256)
conv2k(const float* __restrict__ pw, const float* __restrict__ pred_bias,
       const float* __restrict__ z_ws, unsigned short* __restrict__ Wd,
       float* __restrict__ g0_ws)
{
    const int b = blockIdx.x >> 5, rc = blockIdx.x & 31;
    const int wave = threadIdx.x >> 6, lane = threadIdx.x & 63;
    const float4 ht4 = *(const float4*)(z_ws + b * ZDIM + 512 + 4 * lane);
    const float* src = pw + (size_t)b * GDIM * ZDIM;
    char* dstB = (char*)(Wd + (size_t)b * GDIM * DYNC);

    for (int i = 0; i < 16; ++i) {
        const int row = rc * 64 + wave * 16 + i;
        const float* rs = src + (size_t)row * ZDIM + 4 * lane;
        char* rd = dstB + (size_t)row * (DYNC * 2) + 8 * lane;
        // cols: [0,512) dyn | [512,768) static dot | [768,1280) dyn
        #pragma unroll
        for (int k = 0; k < 2; ++k) {
            const f32x4 f = __builtin_nontemporal_load((const f32x4*)(rs + k * 256));
            u32x2 o; o.x = bfrne_(f.x) | (bfrne_(f.y) << 16);
            o.y = bfrne_(f.z) | (bfrne_(f.w) << 16);
            __builtin_nontemporal_store(o, (u32x2*)(rd + k * 512));
        }
        const f32x4 fs = __builtin_nontemporal_load((const f32x4*)(rs + 512));
        float sp = fs.x * ht4.x + fs.y * ht4.y + fs.z * ht4.z + fs.w * ht4.w;
        #pragma unroll
        for (int k = 0; k < 2; ++k) {
            const f32x4 f = __builtin_nontemporal_load((const f32x4*)(rs + 768 + k * 256));
            u32x2 o; o.x = bfrne_(f.x) | (bfrne_(f.y) << 16);
            o.y = bfrne_(f.z) | (bfrne_(f.w) << 16);
            __builtin_nontemporal_store(o, (u32x2*)(rd + 1024 + k * 512));
        }
        #pragma unroll
        for (int m = 32; m >= 1; m >>= 1) sp += __shfl_xor(sp, m, 64);
        if (lane == 0) g0_ws[b * GDIM + row] = sp + pred_bias[b * GDIM + row];
    }
}

// ---------------- per-step GEMV over folded bf16 weights (R4-proven structure) ----------------
// grid 4096 = 128 samples x 32 chunks; block 256 = 4 waves; wave: 16 rows (8 pairs)
// NO LDS, NO min-waves launch bound -> compiler keeps the double-buffer in VGPRs.
__global__ void __launch_bounds__(256)
matvec2_bf16(const unsigned short* __restrict__ W, const float* __restrict__ z_ws,
             const float* __restrict__ g0_ws, float* __restrict__ g_ws)
{
    const int b = blockIdx.x >> 5, chunk = blockIdx.x & 31;
    const int wave = threadIdx.x >> 6, lane = threadIdx.x & 63;
    const int row0 = chunk * 64 + wave * 16;
    const float* zb = z_ws + b * ZDIM;
    const int l8 = lane * 8;
    // pair layout: slot0 = row r cols[0,512) -> z[0:512); slot1 = row r cols[512,1024) -> z[768:1280)
    //              slot2 = row r+1 cols[0,512) ; slot3 = row r+1 cols[512,1024)
    const float4 pA = *(const float4*)(zb + l8),       pB = *(const float4*)(zb + l8 + 4);
    const float4 qA = *(const float4*)(zb + 768 + l8), qB = *(const float4*)(zb + 768 + l8 + 4);
    const float g0v = (lane < 16) ? g0_ws[b * GDIM + row0 + lane] : 0.f;
    const char* wb = (const char*)W + (size_t)b * GDIM * DYNC * 2;

    #define ISSUE(p, B) { const char* a_ = wb + (size_t)(row0 + 2 * (p)) * (DYNC * 2) + lane * 16; \
        B[0] = __builtin_nontemporal_load((const u32x4*)(a_)); \
        B[1] = __builtin_nontemporal_load((const u32x4*)(a_ + 1024)); \
        B[2] = __builtin_nontemporal_load((const u32x4*)(a_ + 2048)); \
        B[3] = __builtin_nontemporal_load((const u32x4*)(a_ + 3072)); }

    u32x4 bufa[4], bufb[4];
    ISSUE(0, bufa);
    #pragma unroll
    for (int p = 0; p < 8; ++p) {
        u32x4* cur = (p & 1) ? bufb : bufa;
        u32x4* nxt = (p & 1) ? bufa : bufb;
        if (p < 7) ISSUE(p + 1, nxt);
        float accA = 0.f, accB = 0.f;
        dot8_(cur[0], pA, pB, accA); dot8_(cur[1], qA, qB, accA);
        dot8_(cur[2], pA, pB, accB); dot8_(cur[3], qA, qB, accB);
        float s0 = accA + __shfl_xor(accA, 32);
        float s1 = accB + __shfl_xor(accB, 32);
        float u = (lane < 32) ? s0 : s1;
        #pragma unroll
        for (int m = 16; m >= 1; m >>= 1) u += __shfl_xor(u, m);
        const float badd = __shfl(g0v, 2 * p + ((lane >= 32) ? 1 : 0), 64);
        if (lane == 0)       g_ws[b * GDIM + row0 + 2 * p]     = u + badd;
        else if (lane == 32) g_ws[b * GDIM + row0 + 2 * p + 1] = u + badd;
    }
    #undef ISSUE
}

// ---------------- init: state=0, h_target, step-0 encoders ----------------
__global__ void __launch_bounds__(512)
initk(const float* __restrict__ past_root_vel, const float* __restrict__ past_quats,
      const float* __restrict__ past_root_offset, const float* __restrict__ past_quat_offset,
      const float* __restrict__ past_contacts, const float* __restrict__ target_quats,
      const float* __restrict__ init_root_pos,
      const float* __restrict__ se_w1, const float* __restrict__ se_b1,
      const float* __restrict__ se_w2, const float* __restrict__ se_b2,
      const float* __restrict__ oe_w1, const float* __restrict__ oe_b1,
      const float* __restrict__ oe_w2, const float* __restrict__ oe_b2,
      const float* __restrict__ te_w1, const float* __restrict__ te_b1,
      const float* __restrict__ te_w2, const float* __restrict__ te_b2,
      float* __restrict__ z_ws, float* __restrict__ c_ws, float* __restrict__ car_ws)
{
    const int b = blockIdx.x, t = threadIdx.x;
    __shared__ float tq[QD], bufA[512], bufB[512], sv[95], ov[91];

    if (t < 192) car_ws[b * 192 + t] = (t < 3) ? init_root_pos[b * 3 + t] : 0.f;
    c_ws[b * HDIM + t] = 0.f;
    z_ws[b * ZDIM + 768 + t] = 0.f;
    if (t < QD) tq[t] = target_quats[b * QD + t];
    if (t < 4)  sv[t] = past_contacts[b * NPAST * 4 + t];
    if (t < QD) { sv[4 + t] = past_quats[b * NPAST * QD + t];
                  ov[3 + t] = past_quat_offset[b * NPAST * QD + t]; }
    if (t < 3)  { sv[92 + t] = past_root_vel[b * NPAST * 3 + t];
                  ov[t]      = past_root_offset[b * NPAST * 3 + t]; }
    __syncthreads();
    {
        float a = te_b1[t];
        #pragma unroll 8
        for (int i = 0; i < QD; ++i) a = fmaf(tq[i], te_w1[i * 512 + t], a);
        bufA[t] = fmaxf(a, 0.f);
    }
    __syncthreads();
    if (t < 256) {
        float a = te_b2[t];
        #pragma unroll 8
        for (int i = 0; i < 512; ++i) a = fmaf(bufA[i], te_w2[i * 256 + t], a);
        z_ws[b * ZDIM + 512 + t] = fmaxf(a, 0.f);
    }
    __syncthreads();
    {
        float aS = se_b1[t], aO = oe_b1[t];
        #pragma unroll 8
        for (int i = 0; i < 91; ++i) { aS = fmaf(sv[i], se_w1[i * 512 + t], aS);
                                       aO = fmaf(ov[i], oe_w1[i * 512 + t], aO); }
        #pragma unroll
        for (int i = 91; i < 95; ++i) aS = fmaf(sv[i], se_w1[i * 512 + t], aS);
        bufA[t] = fmaxf(aS, 0.f);
        bufB[t] = fmaxf(aO, 0.f);
    }
    __syncthreads();
    if (t < 256) {
        float a = se_b2[t];
        #pragma unroll 8
        for (int i = 0; i < 512; ++i) a = fmaf(bufA[i], se_w2[i * 256 + t], a);
        z_ws[b * ZDIM + t] = fmaxf(a, 0.f);
    } else {
        const int j = t - 256;
        float a = oe_b2[j];
        #pragma unroll 8
        for (int i = 0; i < 512; ++i) a = fmaf(bufB[i], oe_w2[i * 256 + j], a);
        z_ws[b * ZDIM + 256 + j] = fmaxf(a, 0.f);
    }
}

// ---------------- per-step: LSTM + decoder + state update + next encoders (R4-proven) ----------------
__global__ void __launch_bounds__(512)
stepk(const float* __restrict__ past_root_vel, const float* __restrict__ past_quats,
      const float* __restrict__ past_root_offset, const float* __restrict__ past_quat_offset,
      const float* __restrict__ past_contacts, const float* __restrict__ target_root_pos,
      const float* __restrict__ target_quats,
      const float* __restrict__ se_w1, const float* __restrict__ se_b1,
      const float* __restrict__ se_w2, const float* __restrict__ se_b2,
      const float* __restrict__ oe_w1, const float* __restrict__ oe_b1,
      const float* __restrict__ oe_w2, const float* __restrict__ oe_b2,
      const float* __restrict__ de_w1, const float* __restrict__ de_b1,
      const float* __restrict__ de_w2, const float* __restrict__ de_b2,
      const float* __restrict__ de_w3, const float* __restrict__ de_b3,
      float* __restrict__ out, float* __restrict__ z_ws, const float* __restrict__ g_ws,
      float* __restrict__ c_ws, float* __restrict__ car_ws, int s)
{
    const int b = blockIdx.x, t = threadIdx.x;
    __shared__ float4 part4[512];
    __shared__ __align__(16) float h2s[HDIM], bufA[512], bufB[512], d2[256];
    __shared__ float outv[OUTD], nq[QD], sv[95], ov[91], carryL[192], tq[QD], trp[3];
    __shared__ float rvn[3], globn[3], contn[4];

    if (t < 192) carryL[t] = car_ws[b * 192 + t];
    if (t < QD) tq[t] = target_quats[b * QD + t];
    if (t < 3)  trp[t] = target_root_pos[b * 3 + t];

    // LSTM (gates already include bias + static h_target part via g0 fold)
    {
        const float* g = g_ws + b * GDIM;
        const float ig = g[t], fg = g[512 + t], gg = g[1024 + t], og = g[1536 + t];
        const float c2 = sig_(fg) * c_ws[b * HDIM + t] + sig_(ig) * tanhf(gg);
        c_ws[b * HDIM + t] = c2;
        const float h2 = sig_(og) * tanhf(c2);
        h2s[t] = h2;
        z_ws[b * ZDIM + 768 + t] = h2;
    }
    __syncthreads();
    // decoder L1: 512 -> 512
    {
        const int c = t & 127, s4 = t >> 7;
        float4 acc = {0.f, 0.f, 0.f, 0.f};
        const float* w = de_w1 + (size_t)(s4 * 128) * 512 + 4 * c;
        #pragma unroll 8
        for (int k = 0; k < 128; ++k)
            fma4_(acc, h2s[s4 * 128 + k], *(const float4*)(w + (size_t)k * 512));
        part4[t] = acc;
    }
    __syncthreads();
    if (t < 128) {
        float4 v = part4[t];
        #pragma unroll
        for (int s4 = 1; s4 < 4; ++s4) { const float4 p = part4[s4 * 128 + t];
            v.x += p.x; v.y += p.y; v.z += p.z; v.w += p.w; }
        const float4 bb = *(const float4*)(de_b1 + 4 * t);
        float4 r; r.x = fmaxf(v.x + bb.x, 0.f); r.y = fmaxf(v.y + bb.y, 0.f);
        r.z = fmaxf(v.z + bb.z, 0.f); r.w = fmaxf(v.w + bb.w, 0.f);
        *(float4*)&bufA[4 * t] = r;
    }
    __syncthreads();
    // decoder L2: 512 -> 256
    {
        const int c = t & 63, s8 = t >> 6;
        float4 acc = {0.f, 0.f, 0.f, 0.f};
        const float* w = de_w2 + (size_t)(s8 * 64) * 256 + 4 * c;
        #pragma unroll 8
        for (int k = 0; k < 64; ++k)
            fma4_(acc, bufA[s8 * 64 + k], *(const float4*)(w + (size_t)k * 256));
        part4[t] = acc;
    }
    __syncthreads();
    if (t < 64) {
        float4 v = part4[t];
        #pragma unroll
        for (int s8 = 1; s8 < 8; ++s8) { const float4 p = part4[s8 * 64 + t];
            v.x += p.x; v.y += p.y; v.z += p.z; v.w += p.w; }
        const float4 bb = *(const float4*)(de_b2 + 4 * t);
        float4 r; r.x = fmaxf(v.x + bb.x, 0.f); r.y = fmaxf(v.y + bb.y, 0.f);
        r.z = fmaxf(v.z + bb.z, 0.f); r.w = fmaxf(v.w + bb.w, 0.f);
        *(float4*)&d2[4 * t] = r;
    }
    __syncthreads();
    // decoder L3: 256 -> 95
    if (t < OUTD) {
        float acc = de_b3[t];
        #pragma unroll 16
        for (int i = 0; i < 256; ++i) acc = fmaf(d2[i], de_w3[i * OUTD + t], acc);
        outv[t] = acc;
    }
    __syncthreads();

    const bool pastS = (s < NPAST);
    if (t < QD) {
        const float qin = pastS ? past_quats[(b * NPAST + s) * QD + t] : carryL[10 + t];
        nq[t] = outv[t] + qin;
    }
    __syncthreads();
    if (t < 22) {
        const float a = nq[4 * t], b2 = nq[4 * t + 1], c3 = nq[4 * t + 2], d4 = nq[4 * t + 3];
        const float inv = 1.f / fmaxf(sqrtf(a * a + b2 * b2 + c3 * c3 + d4 * d4), 1e-12f);
        nq[4 * t] = a * inv; nq[4 * t + 1] = b2 * inv; nq[4 * t + 2] = c3 * inv; nq[4 * t + 3] = d4 * inv;
    }
    if (t < 3) {
        const float rin = pastS ? past_root_vel[(b * NPAST + s) * 3 + t] : carryL[3 + t];
        const float nrv = outv[88 + t] + rin;
        const float g = carryL[t] + (pastS ? rin : nrv);
        rvn[t] = nrv; globn[t] = g;
    }
    if (t < 4) contn[t] = sig_(outv[91 + t]);
    __syncthreads();

    if (t < 3) { car_ws[b * 192 + t] = globn[t]; car_ws[b * 192 + 3 + t] = rvn[t];
                 car_ws[b * 192 + 186 + t] = globn[t] - trp[t]; }
    if (t < 4) car_ws[b * 192 + 6 + t] = contn[t];
    if (t < QD) { car_ws[b * 192 + 10 + t] = nq[t]; car_ws[b * 192 + 98 + t] = nq[t] - tq[t]; }
    if (s == NPAST - 1) {
        const size_t pb = (size_t)b * 30 * 91;
        if (t < 3)  out[pb + t] = rvn[t];
        if (t < QD) out[pb + 3 + t] = nq[t];
        if (t < 4)  out[POSE_ELEMS + (size_t)b * 30 * 4 + t] = contn[t];
    } else if (!pastS) {
        const int k = s - NPAST + 1;
        const size_t pb = ((size_t)b * 30 + k) * 91;
        if (t < 3)  out[pb + t] = globn[t];
        if (t < QD) out[pb + 3 + t] = nq[t];
        if (t < 4)  out[POSE_ELEMS + ((size_t)b * 30 + k) * 4 + t] = contn[t];
    }
    if (s == NSTEPS - 1) return;

    const int nx = s + 1;
    if (nx < NPAST) {
        if (t < 4)  sv[t] = past_contacts[(b * NPAST + nx) * 4 + t];
        if (t < QD) { sv[4 + t] = past_quats[(b * NPAST + nx) * QD + t];
                      ov[3 + t] = past_quat_offset[(b * NPAST + nx) * QD + t]; }
        if (t < 3)  { sv[92 + t] = past_root_vel[(b * NPAST + nx) * 3 + t];
                      ov[t]      = past_root_offset[(b * NPAST + nx) * 3 + t]; }
    } else {
        if (t < 4)  sv[t] = contn[t];
        if (t < QD) { sv[4 + t] = nq[t]; ov[3 + t] = nq[t] - tq[t]; }
        if (t < 3)  { sv[92 + t] = rvn[t]; ov[t] = globn[t] - trp[t]; }
    }
    __syncthreads();
    {
        const int tt = t & 255, enc = t >> 8;
        const int c = tt & 127, sl = tt >> 7;
        const float* inp = enc ? ov : sv;
        const float* w1  = enc ? oe_w1 : se_w1;
        const int nin  = enc ? 91 : 95;
        const int half = enc ? 46 : 48;
        const int i0 = sl * half;
        const int iend = (i0 + half < nin) ? (i0 + half) : nin;
        float4 acc = {0.f, 0.f, 0.f, 0.f};
        #pragma unroll 8
        for (int k = 0; k < 48; ++k) {
            const int i = i0 + k;
            if (i < iend) fma4_(acc, inp[i], *(const float4*)(w1 + (size_t)i * 512 + 4 * c));
        }
        part4[enc * 256 + tt] = acc;
    }
    __syncthreads();
    if (t < 128) {
        const float4 a = part4[t], b2 = part4[128 + t];
        const float4 bb = *(const float4*)(se_b1 + 4 * t);
        float4 r; r.x = fmaxf(a.x + b2.x + bb.x, 0.f); r.y = fmaxf(a.y + b2.y + bb.y, 0.f);
        r.z = fmaxf(a.z + b2.z + bb.z, 0.f); r.w = fmaxf(a.w + b2.w + bb.w, 0.f);
        *(float4*)&bufA[4 * t] = r;
    } else if (t < 256) {
        const int c = t - 128;
        const float4 a = part4[256 + c], b2 = part4[384 + c];
        const float4 bb = *(const float4*)(oe_b1 + 4 * c);
        float4 r; r.x = fmaxf(a.x + b2.x + bb.x, 0.f); r.y = fmaxf(a.y + b2.y + bb.y, 0.f);
        r.z = fmaxf(a.z + b2.z + bb.z, 0.f); r.w = fmaxf(a.w + b2.w + bb.w, 0.f);
        *(float4*)&bufB[4 * c] = r;
    }
    __syncthreads();
    {
        const int tt = t & 255, enc = t >> 8;
        const int c = tt & 63, sl = tt >> 6;
        const float* inp = enc ? bufB : bufA;
        const float* w2  = enc ? oe_w2 : se_w2;
        float4 acc = {0.f, 0.f, 0.f, 0.f};
        const float* w = w2 + (size_t)(sl * 128) * 256 + 4 * c;
        #pragma unroll 8
        for (int k = 0; k < 128; ++k)
            fma4_(acc, inp[sl * 128 + k], *(const float4*)(w + (size_t)k * 256));
        part4[enc * 256 + tt] = acc;
    }
    __syncthreads();
    if (t < 64) {
        float4 v = part4[t];
        #pragma unroll
        for (int sl = 1; sl < 4; ++sl) { const float4 p = part4[sl * 64 + t];
            v.x += p.x; v.y += p.y; v.z += p.z; v.w += p.w; }
        const float4 bb = *(const float4*)(se_b2 + 4 * t);
        float4 r; r.x = fmaxf(v.x + bb.x, 0.f); r.y = fmaxf(v.y + bb.y, 0.f);
        r.z = fmaxf(v.z + bb.z, 0.f); r.w = fmaxf(v.w + bb.w, 0.f);
        *(float4*)(z_ws + b * ZDIM + 4 * t) = r;
    } else if (t < 128) {
        const int c = t - 64;
        float4 v = part4[256 + c];
        #pragma unroll
        for (int sl = 1; sl < 4; ++sl) { const float4 p = part4[256 + sl * 64 + c];
            v.x += p.x; v.y += p.y; v.z += p.z; v.w += p.w; }
        const float4 bb = *(const float4*)(oe_b2 + 4 * c);
        float4 r; r.x = fmaxf(v.x + bb.x, 0.f); r.y = fmaxf(v.y + bb.y, 0.f);
        r.z = fmaxf(v.z + bb.z, 0.f); r.w = fmaxf(v.w + bb.w, 0.f);
        *(float4*)(z_ws + b * ZDIM + 256 + 4 * c) = r;
    }
}

// ================= fp32 fallback path (ws too small): R4 kernel =================
__global__ void __launch_bounds__(256)
matvec_f32(const float* __restrict__ W, const float* __restrict__ z_ws,
           const float* __restrict__ pred_bias, float* __restrict__ g_ws)
{
    const int b = blockIdx.x >> 5, chunk = blockIdx.x & 31;
    const int wave = threadIdx.x >> 6, lane = threadIdx.x & 63;
    const int row0 = chunk * 64 + wave * 16;
    const float* zb = z_ws + b * ZDIM;
    const float biasv = (lane < 16) ? pred_bias[b * GDIM + row0 + lane] : 0.f;
    const int l4 = lane * 4;
    const float4 z0 = *(const float4*)(zb + l4);
    const float4 z1 = *(const float4*)(zb + 256 + l4);
    const float4 z2 = *(const float4*)(zb + 512 + l4);
    const float4 z3 = *(const float4*)(zb + 768 + l4);
    const float4 z4 = *(const float4*)(zb + 1024 + l4);
    const char* wb = (const char*)W + (size_t)b * GDIM * ZDIM * 4;

    #define ISSUE(p, B) { const char* a_ = wb + (size_t)(row0 + 2 * (p)) * (ZDIM * 4) + lane * 16; \
        _Pragma("unroll") for (int i = 0; i < 10; ++i) B[i] = *(const uint4*)(a_ + i * 1024); }

    uint4 bufa[10], bufb[10];
    ISSUE(0, bufa);
    #pragma unroll
    for (int p = 0; p < 8; ++p) {
        uint4* cur = (p & 1) ? bufb : bufa;
        uint4* nxt = (p & 1) ? bufa : bufb;
        if (p < 7) ISSUE(p + 1, nxt);
        float accA = 0.f, accB = 0.f;
        dot4_(cur[0], z0, accA); dot4_(cur[1], z1, accA); dot4_(cur[2], z2, accA);
        dot4_(cur[3], z3, accA); dot4_(cur[4], z4, accA);
        dot4_(cur[5], z0, accB); dot4_(cur[6], z1, accB); dot4_(cur[7], z2, accB);
        dot4_(cur[8], z3, accB); dot4_(cur[9], z4, accB);
        float s0 = accA + __shfl_xor(accA, 32);
        float s1 = accB + __shfl_xor(accB, 32);
        float u = (lane < 32) ? s0 : s1;
        #pragma unroll
        for (int m = 16; m >= 1; m >>= 1) u += __shfl_xor(u, m);
        const float badd = __shfl(biasv, 2 * p + ((lane >= 32) ? 1 : 0), 64);
        if (lane == 0)       g_ws[b * GDIM + row0 + 2 * p]     = u + badd;
        else if (lane == 32) g_ws[b * GDIM + row0 + 2 * p + 1] = u + badd;
    }
    #undef ISSUE
}

extern "C" void kernel_launch(void* const* d_in, const int* in_sizes, int n_in,
                              void* d_out, int out_size, void* d_ws, size_t ws_size,
                              hipStream_t stream) {
    const float* prv = (const float*)d_in[0];
    const float* pq  = (const float*)d_in[1];
    const float* pro = (const float*)d_in[2];
    const float* pqo = (const float*)d_in[3];
    const float* pc  = (const float*)d_in[4];
    const float* trp = (const float*)d_in[5];
    const float* tq  = (const float*)d_in[6];
    const float* irp = (const float*)d_in[7];
    const float* pw  = (const float*)d_in[8];
    const float* pb  = (const float*)d_in[9];
    const float* se_w1 = (const float*)d_in[10]; const float* se_b1 = (const float*)d_in[11];
    const float* se_w2 = (const float*)d_in[12]; const float* se_b2 = (const float*)d_in[13];
    const float* oe_w1 = (const float*)d_in[14]; const float* oe_b1 = (const float*)d_in[15];
    const float* oe_w2 = (const float*)d_in[16]; const float* oe_b2 = (const float*)d_in[17];
    const float* te_w1 = (const float*)d_in[18]; const float* te_b1 = (const float*)d_in[19];
    const float* te_w2 = (const float*)d_in[20]; const float* te_b2 = (const float*)d_in[21];
    const float* de_w1 = (const float*)d_in[22]; const float* de_b1 = (const float*)d_in[23];
    const float* de_w2 = (const float*)d_in[24]; const float* de_b2 = (const float*)d_in[25];
    const float* de_w3 = (const float*)d_in[26]; const float* de_b3 = (const float*)d_in[27];
    float* outp = (float*)d_out;

    const size_t WB2  = (size_t)BATCH * GDIM * DYNC * 2;   // bf16 dynamic weights
    const size_t AUXB = (size_t)BATCH * (GDIM + ZDIM + GDIM + HDIM + 192) * 4;
    const bool bf = ws_size >= WB2 + AUXB;

    char* base = (char*)d_ws;
    float* g0_ws; float* z_ws;
    if (bf) {
        g0_ws  = (float*)(base + WB2);
        z_ws   = g0_ws + (size_t)BATCH * GDIM;
    } else {
        g0_ws  = nullptr;
        z_ws   = (float*)base;
    }
    float* g_ws   = z_ws + (size_t)BATCH * ZDIM;
    float* c_ws   = g_ws + (size_t)BATCH * GDIM;
    float* car_ws = c_ws + (size_t)BATCH * HDIM;

    initk<<<dim3(BATCH), dim3(512), 0, stream>>>(prv, pq, pro, pqo, pc, tq, irp,
        se_w1, se_b1, se_w2, se_b2, oe_w1, oe_b1, oe_w2, oe_b2,
        te_w1, te_b1, te_w2, te_b2, z_ws, c_ws, car_ws);

    if (bf) {
        conv2k<<<dim3(BATCH * 32), dim3(256), 0, stream>>>(pw, pb, z_ws,
            (unsigned short*)d_ws, g0_ws);
        for (int s = 0; s < NSTEPS; ++s) {
            matvec2_bf16<<<dim3(BATCH * 32), dim3(256), 0, stream>>>(
                (const unsigned short*)d_ws, z_ws, g0_ws, g_ws);
            stepk<<<dim3(BATCH), dim3(512), 0, stream>>>(prv, pq, pro, pqo, pc, trp, tq,
                se_w1, se_b1, se_w2, se_b2, oe_w1, oe_b1, oe_w2, oe_b2,
                de_w1, de_b1, de_w2, de_b2, de_w3, de_b3,
                outp, z_ws, g_ws, c_ws, car_ws, s);
        }
    } else {
        for (int s = 0; s < NSTEPS; ++s) {
            matvec_f32<<<dim3(BATCH * 32), dim3(256), 0, stream>>>(pw, z_ws, pb, g_ws);
            stepk<<<dim3(BATCH), dim3(512), 0, stream>>>(prv, pq, pro, pqo, pc, trp, tq,
                se_w1, se_b1, se_w2, se_b2, oe_w1, oe_b1, oe_w2, oe_b2,
                de_w1, de_b1, de_w2, de_b2, de_w3, de_b3,
                outp, z_ws, g_ws, c_ws, car_ws, s);
        }
    }
}

// Round 8
// 5373.656 us; speedup vs baseline: 8.5592x; 1.0092x over previous
//
#include <hip/hip_runtime.h>
#include <hip/hip_bf16.h>
#include <math.h>

#define BATCH 128
#define QD 88
#define HDIM 512
#define ZDIM 1280
#define GDIM 2048
#define DYNC 1024          // dynamic cols after folding static h_target block
#define NPAST 10
#define NTRANS 29
#define NSTEPS (NPAST + NTRANS)
#define OUTD 95
#define POSE_ELEMS (BATCH * 30 * 91)

typedef float f32x4 __attribute__((ext_vector_type(4)));
typedef unsigned int u32x4 __attribute__((ext_vector_type(4)));
typedef unsigned int u32x2 __attribute__((ext_vector_type(2)));

__device__ __forceinline__ float sig_(float x) { return 1.0f / (1.0f + expf(-x)); }
__device__ __forceinline__ float bflo_(unsigned u) { return __uint_as_float(u << 16); }
__device__ __forceinline__ float bfhi_(unsigned u) { return __uint_as_float(u & 0xffff0000u); }
__device__ __forceinline__ unsigned bfrne_(float f) {
    return (__float_as_uint(f) + 0x7fffu + ((__float_as_uint(f) >> 16) & 1u)) >> 16;
}
__device__ __forceinline__ void dot8_(const u32x4 wv, const float4 za, const float4 zb,
                                      float& d) {
    d = fmaf(bflo_(wv.x), za.x, d); d = fmaf(bfhi_(wv.x), za.y, d);
    d = fmaf(bflo_(wv.y), za.z, d); d = fmaf(bfhi_(wv.y), za.w, d);
    d = fmaf(bflo_(wv.z), zb.x, d); d = fmaf(bfhi_(wv.z), zb.y, d);
    d = fmaf(bflo_(wv.w), zb.z, d); d = fmaf(bfhi_(wv.w), zb.w, d);
}
__device__ __forceinline__ void dot4_(const uint4 wv, const float4 zv, float& d) {
    const float4 f = *(const float4*)&wv;
    d = fmaf(f.x, zv.x, d); d = fmaf(f.y, zv.y, d);
    d = fmaf(f.z, zv.z, d); d = fmaf(f.w, zv.w, d);
}
__device__ __forceinline__ void fma4_(float4& acc, float x, const float4 w) {
    acc.x = fmaf(x, w.x, acc.x); acc.y = fmaf(x, w.y, acc.y);
    acc.z = fmaf(x, w.z, acc.z); acc.w = fmaf(x, w.w, acc.w);
}
__device__ __forceinline__ u32x2 pk2_(const uint4 v) {
    u32x2 o;
    o.x = bfrne_(__uint_as_float(v.x)) | (bfrne_(__uint_as_float(v.y)) << 16);
    o.y = bfrne_(__uint_as_float(v.z)) | (bfrne_(__uint_as_float(v.w)) << 16);
    return o;
}

// ---- step-0 GEMV over fp32 weights, fused with bf16 conversion + static fold ----
// grid 4096 = 128 x 32 chunks; block 256 = 4 waves; wave: 16 rows (8 pairs)
// Writes: Wd (bf16 dynamic cols), g0 = bias + W[:,512:768].h_tgt, g = full step-0 gates.
__global__ void __launch_bounds__(256)
matvec0_conv(const float* __restrict__ W, const float* __restrict__ z_ws,
             const float* __restrict__ pred_bias, unsigned short* __restrict__ Wd,
             float* __restrict__ g_ws, float* __restrict__ g0_ws)
{
    const int b = blockIdx.x >> 5, chunk = blockIdx.x & 31;
    const int wave = threadIdx.x >> 6, lane = threadIdx.x & 63;
    const int row0 = chunk * 64 + wave * 16;
    const float* zb = z_ws + b * ZDIM;
    const float biasv = (lane < 16) ? pred_bias[b * GDIM + row0 + lane] : 0.f;
    const int l4 = lane * 4;
    const float4 z0 = *(const float4*)(zb + l4);          // cols 0..255
    const float4 z1 = *(const float4*)(zb + 256 + l4);    // cols 256..511
    const float4 zh = *(const float4*)(zb + 512 + l4);    // cols 512..767 (h_target, static)
    const float4 z3 = *(const float4*)(zb + 768 + l4);    // cols 768..1023 (h)
    const float4 z4 = *(const float4*)(zb + 1024 + l4);   // cols 1024..1279 (h)
    const char* wb = (const char*)W + (size_t)b * GDIM * ZDIM * 4;
    char* dstB = (char*)(Wd + (size_t)b * GDIM * DYNC);

    #define ISSUE(p, B) { const char* a_ = wb + (size_t)(row0 + 2 * (p)) * (ZDIM * 4) + lane * 16; \
        _Pragma("unroll") for (int i = 0; i < 10; ++i) B[i] = *(const uint4*)(a_ + i * 1024); }

    uint4 bufa[10], bufb[10];
    ISSUE(0, bufa);
    #pragma unroll
    for (int p = 0; p < 8; ++p) {
        uint4* cur = (p & 1) ? bufb : bufa;
        uint4* nxt = (p & 1) ? bufa : bufb;
        if (p < 7) ISSUE(p + 1, nxt);
        float dynA = 0.f, dynB = 0.f, statA = 0.f, statB = 0.f;
        dot4_(cur[0], z0, dynA); dot4_(cur[1], z1, dynA);
        dot4_(cur[2], zh, statA);
        dot4_(cur[3], z3, dynA); dot4_(cur[4], z4, dynA);
        dot4_(cur[5], z0, dynB); dot4_(cur[6], z1, dynB);
        dot4_(cur[7], zh, statB);
        dot4_(cur[8], z3, dynB); dot4_(cur[9], z4, dynB);
        // bf16 pack + store of dynamic slots (row r: cur[0,1,3,4]; row r+1: cur[5,6,8,9])
        // dyn layout per row: [cols 0..511 | cols 768..1279]; lane covers 4 cols per slot.
        {
            char* rd = dstB + (size_t)(row0 + 2 * p) * (DYNC * 2) + 8 * lane;
            __builtin_nontemporal_store(pk2_(cur[0]), (u32x2*)(rd));
            __builtin_nontemporal_store(pk2_(cur[1]), (u32x2*)(rd + 512));
            __builtin_nontemporal_store(pk2_(cur[3]), (u32x2*)(rd + 1024));
            __builtin_nontemporal_store(pk2_(cur[4]), (u32x2*)(rd + 1536));
            char* rd2 = rd + (DYNC * 2);
            __builtin_nontemporal_store(pk2_(cur[5]), (u32x2*)(rd2));
            __builtin_nontemporal_store(pk2_(cur[6]), (u32x2*)(rd2 + 512));
            __builtin_nontemporal_store(pk2_(cur[8]), (u32x2*)(rd2 + 1024));
            __builtin_nontemporal_store(pk2_(cur[9]), (u32x2*)(rd2 + 1536));
        }
        float sd0 = dynA + __shfl_xor(dynA, 32);
        float sd1 = dynB + __shfl_xor(dynB, 32);
        float ud = (lane < 32) ? sd0 : sd1;
        float ss0 = statA + __shfl_xor(statA, 32);
        float ss1 = statB + __shfl_xor(statB, 32);
        float us = (lane < 32) ? ss0 : ss1;
        #pragma unroll
        for (int m = 16; m >= 1; m >>= 1) { ud += __shfl_xor(ud, m); us += __shfl_xor(us, m); }
        const float badd = __shfl(biasv, 2 * p + ((lane >= 32) ? 1 : 0), 64);
        if (lane == 0 || lane == 32) {
            const int r = row0 + 2 * p + ((lane >= 32) ? 1 : 0);
            g0_ws[b * GDIM + r] = us + badd;
            g_ws[b * GDIM + r]  = ud + us + badd;
        }
    }
    #undef ISSUE
}

// ---------------- per-step GEMV over folded bf16 weights, depth-2 prefetch ----------------
// grid 4096 = 128 samples x 32 chunks; block 256 = 4 waves; wave: 16 rows (8 pairs)
__global__ void __launch_bounds__(256)
matvec2_bf16(const unsigned short* __restrict__ W, const float* __restrict__ z_ws,
             const float* __restrict__ g0_ws, float* __restrict__ g_ws)
{
    const int b = blockIdx.x >> 5, chunk = blockIdx.x & 31;
    const int wave = threadIdx.x >> 6, lane = threadIdx.x & 63;
    const int row0 = chunk * 64 + wave * 16;
    const float* zb = z_ws + b * ZDIM;
    const int l8 = lane * 8;
    const float4 pA = *(const float4*)(zb + l8),       pB = *(const float4*)(zb + l8 + 4);
    const float4 qA = *(const float4*)(zb + 768 + l8), qB = *(const float4*)(zb + 768 + l8 + 4);
    const float g0v = (lane < 16) ? g0_ws[b * GDIM + row0 + lane] : 0.f;
    const char* wb = (const char*)W + (size_t)b * GDIM * DYNC * 2;

    #define ISSUE(p, B) { const char* a_ = wb + (size_t)(row0 + 2 * (p)) * (DYNC * 2) + lane * 16; \
        B[0] = __builtin_nontemporal_load((const u32x4*)(a_)); \
        B[1] = __builtin_nontemporal_load((const u32x4*)(a_ + 1024)); \
        B[2] = __builtin_nontemporal_load((const u32x4*)(a_ + 2048)); \
        B[3] = __builtin_nontemporal_load((const u32x4*)(a_ + 3072)); }

    u32x4 buf0[4], buf1[4], buf2[4];
    ISSUE(0, buf0);
    ISSUE(1, buf1);
    #pragma unroll
    for (int p = 0; p < 8; ++p) {
        u32x4* cur = (p % 3 == 0) ? buf0 : (p % 3 == 1) ? buf1 : buf2;
        u32x4* nxt = ((p + 2) % 3 == 0) ? buf0 : ((p + 2) % 3 == 1) ? buf1 : buf2;
        if (p < 6) ISSUE(p + 2, nxt);
        float accA = 0.f, accB = 0.f;
        dot8_(cur[0], pA, pB, accA); dot8_(cur[1], qA, qB, accA);
        dot8_(cur[2], pA, pB, accB); dot8_(cur[3], qA, qB, accB);
        float s0 = accA + __shfl_xor(accA, 32);
        float s1 = accB + __shfl_xor(accB, 32);
        float u = (lane < 32) ? s0 : s1;
        #pragma unroll
        for (int m = 16; m >= 1; m >>= 1) u += __shfl_xor(u, m);
        const float badd = __shfl(g0v, 2 * p + ((lane >= 32) ? 1 : 0), 64);
        if (lane == 0)       g_ws[b * GDIM + row0 + 2 * p]     = u + badd;
        else if (lane == 32) g_ws[b * GDIM + row0 + 2 * p + 1] = u + badd;
    }
    #undef ISSUE
}

// ---------------- init: state=0, h_target, step-0 encoders ----------------
__global__ void __launch_bounds__(512)
initk(const float* __restrict__ past_root_vel, const float* __restrict__ past_quats,
      const float* __restrict__ past_root_offset, const float* __restrict__ past_quat_offset,
      const float* __restrict__ past_contacts, const float* __restrict__ target_quats,
      const float* __restrict__ init_root_pos,
      const float* __restrict__ se_w1, const float* __restrict__ se_b1,
      const float* __restrict__ se_w2, const float* __restrict__ se_b2,
      const float* __restrict__ oe_w1, const float* __restrict__ oe_b1,
      const float* __restrict__ oe_w2, const float* __restrict__ oe_b2,
      const float* __restrict__ te_w1, const float* __restrict__ te_b1,
      const float* __restrict__ te_w2, const float* __restrict__ te_b2,
      float* __restrict__ z_ws, float* __restrict__ c_ws, float* __restrict__ car_ws)
{
    const int b = blockIdx.x, t = threadIdx.x;
    __shared__ float tq[QD], bufA[512], bufB[512], sv[95], ov[91];

    if (t < 192) car_ws[b * 192 + t] = (t < 3) ? init_root_pos[b * 3 + t] : 0.f;
    c_ws[b * HDIM + t] = 0.f;
    z_ws[b * ZDIM + 768 + t] = 0.f;
    if (t < QD) tq[t] = target_quats[b * QD + t];
    if (t < 4)  sv[t] = past_contacts[b * NPAST * 4 + t];
    if (t < QD) { sv[4 + t] = past_quats[b * NPAST * QD + t];
                  ov[3 + t] = past_quat_offset[b * NPAST * QD + t]; }
    if (t < 3)  { sv[92 + t] = past_root_vel[b * NPAST * 3 + t];
                  ov[t]      = past_root_offset[b * NPAST * 3 + t]; }
    __syncthreads();
    {
        float a = te_b1[t];
        #pragma unroll 8
        for (int i = 0; i < QD; ++i) a = fmaf(tq[i], te_w1[i * 512 + t], a);
        bufA[t] = fmaxf(a, 0.f);
    }
    __syncthreads();
    if (t < 256) {
        float a = te_b2[t];
        #pragma unroll 8
        for (int i = 0; i < 512; ++i) a = fmaf(bufA[i], te_w2[i * 256 + t], a);
        z_ws[b * ZDIM + 512 + t] = fmaxf(a, 0.f);
    }
    __syncthreads();
    {
        float aS = se_b1[t], aO = oe_b1[t];
        #pragma unroll 8
        for (int i = 0; i < 91; ++i) { aS = fmaf(sv[i], se_w1[i * 512 + t], aS);
                                       aO = fmaf(ov[i], oe_w1[i * 512 + t], aO); }
        #pragma unroll
        for (int i = 91; i < 95; ++i) aS = fmaf(sv[i], se_w1[i * 512 + t], aS);
        bufA[t] = fmaxf(aS, 0.f);
        bufB[t] = fmaxf(aO, 0.f);
    }
    __syncthreads();
    if (t < 256) {
        float a = se_b2[t];
        #pragma unroll 8
        for (int i = 0; i < 512; ++i) a = fmaf(bufA[i], se_w2[i * 256 + t], a);
        z_ws[b * ZDIM + t] = fmaxf(a, 0.f);
    } else {
        const int j = t - 256;
        float a = oe_b2[j];
        #pragma unroll 8
        for (int i = 0; i < 512; ++i) a = fmaf(bufB[i], oe_w2[i * 256 + j], a);
        z_ws[b * ZDIM + 256 + j] = fmaxf(a, 0.f);
    }
}

// ---------------- per-step: LSTM + decoder + state update + next encoders ----------------
__global__ void __launch_bounds__(512)
stepk(const float* __restrict__ past_root_vel, const float* __restrict__ past_quats,
      const float* __restrict__ past_root_offset, const float* __restrict__ past_quat_offset,
      const float* __restrict__ past_contacts, const float* __restrict__ target_root_pos,
      const float* __restrict__ target_quats,
      const float* __restrict__ se_w1, const float* __restrict__ se_b1,
      const float* __restrict__ se_w2, const float* __restrict__ se_b2,
      const float* __restrict__ oe_w1, const float* __restrict__ oe_b1,
      const float* __restrict__ oe_w2, const float* __restrict__ oe_b2,
      const float* __restrict__ de_w1, const float* __restrict__ de_b1,
      const float* __restrict__ de_w2, const float* __restrict__ de_b2,
      const float* __restrict__ de_w3, const float* __restrict__ de_b3,
      float* __restrict__ out, float* __restrict__ z_ws, const float* __restrict__ g_ws,
      float* __restrict__ c_ws, float* __restrict__ car_ws, int s)
{
    const int b = blockIdx.x, t = threadIdx.x;
    __shared__ float4 part4[512];
    __shared__ __align__(16) float h2s[HDIM], bufA[512], bufB[512], d2[256];
    __shared__ float outv[OUTD], nq[QD], sv[95], ov[91], carryL[192], tq[QD], trp[3];
    __shared__ float rvn[3], globn[3], contn[4];

    if (t < 192) carryL[t] = car_ws[b * 192 + t];
    if (t < QD) tq[t] = target_quats[b * QD + t];
    if (t < 3)  trp[t] = target_root_pos[b * 3 + t];

    // LSTM (gates already include bias + static h_target part via g0 fold)
    {
        const float* g = g_ws + b * GDIM;
        const float ig = g[t], fg = g[512 + t], gg = g[1024 + t], og = g[1536 + t];
        const float c2 = sig_(fg) * c_ws[b * HDIM + t] + sig_(ig) * tanhf(gg);
        c_ws[b * HDIM + t] = c2;
        const float h2 = sig_(og) * tanhf(c2);
        h2s[t] = h2;
        z_ws[b * ZDIM + 768 + t] = h2;
    }
    __syncthreads();
    // decoder L1: 512 -> 512
    {
        const int c = t & 127, s4 = t >> 7;
        float4 acc = {0.f, 0.f, 0.f, 0.f};
        const float* w = de_w1 + (size_t)(s4 * 128) * 512 + 4 * c;
        #pragma unroll 8
        for (int k = 0; k < 128; ++k)
            fma4_(acc, h2s[s4 * 128 + k], *(const float4*)(w + (size_t)k * 512));
        part4[t] = acc;
    }
    __syncthreads();
    if (t < 128) {
        float4 v = part4[t];
        #pragma unroll
        for (int s4 = 1; s4 < 4; ++s4) { const float4 p = part4[s4 * 128 + t];
            v.x += p.x; v.y += p.y; v.z += p.z; v.w += p.w; }
        const float4 bb = *(const float4*)(de_b1 + 4 * t);
        float4 r; r.x = fmaxf(v.x + bb.x, 0.f); r.y = fmaxf(v.y + bb.y, 0.f);
        r.z = fmaxf(v.z + bb.z, 0.f); r.w = fmaxf(v.w + bb.w, 0.f);
        *(float4*)&bufA[4 * t] = r;
    }
    __syncthreads();
    // decoder L2: 512 -> 256
    {
        const int c = t & 63, s8 = t >> 6;
        float4 acc = {0.f, 0.f, 0.f, 0.f};
        const float* w = de_w2 + (size_t)(s8 * 64) * 256 + 4 * c;
        #pragma unroll 8
        for (int k = 0; k < 64; ++k)
            fma4_(acc, bufA[s8 * 64 + k], *(const float4*)(w + (size_t)k * 256));
        part4[t] = acc;
    }
    __syncthreads();
    if (t < 64) {
        float4 v = part4[t];
        #pragma unroll
        for (int s8 = 1; s8 < 8; ++s8) { const float4 p = part4[s8 * 64 + t];
            v.x += p.x; v.y += p.y; v.z += p.z; v.w += p.w; }
        const float4 bb = *(const float4*)(de_b2 + 4 * t);
        float4 r; r.x = fmaxf(v.x + bb.x, 0.f); r.y = fmaxf(v.y + bb.y, 0.f);
        r.z = fmaxf(v.z + bb.z, 0.f); r.w = fmaxf(v.w + bb.w, 0.f);
        *(float4*)&d2[4 * t] = r;
    }
    __syncthreads();
    // decoder L3: 256 -> 95
    if (t < OUTD) {
        float acc = de_b3[t];
        #pragma unroll 16
        for (int i = 0; i < 256; ++i) acc = fmaf(d2[i], de_w3[i * OUTD + t], acc);
        outv[t] = acc;
    }
    __syncthreads();

    const bool pastS = (s < NPAST);
    if (t < QD) {
        const float qin = pastS ? past_quats[(b * NPAST + s) * QD + t] : carryL[10 + t];
        nq[t] = outv[t] + qin;
    }
    __syncthreads();
    if (t < 22) {
        const float a = nq[4 * t], b2 = nq[4 * t + 1], c3 = nq[4 * t + 2], d4 = nq[4 * t + 3];
        const float inv = 1.f / fmaxf(sqrtf(a * a + b2 * b2 + c3 * c3 + d4 * d4), 1e-12f);
        nq[4 * t] = a * inv; nq[4 * t + 1] = b2 * inv; nq[4 * t + 2] = c3 * inv; nq[4 * t + 3] = d4 * inv;
    }
    if (t < 3) {
        const float rin = pastS ? past_root_vel[(b * NPAST + s) * 3 + t] : carryL[3 + t];
        const float nrv = outv[88 + t] + rin;
        const float g = carryL[t] + (pastS ? rin : nrv);
        rvn[t] = nrv; globn[t] = g;
    }
    if (t < 4) contn[t] = sig_(outv[91 + t]);
    __syncthreads();

    if (t < 3) { car_ws[b * 192 + t] = globn[t]; car_ws[b * 192 + 3 + t] = rvn[t];
                 car_ws[b * 192 + 186 + t] = globn[t] - trp[t]; }
    if (t < 4) car_ws[b * 192 + 6 + t] = contn[t];
    if (t < QD) { car_ws[b * 192 + 10 + t] = nq[t]; car_ws[b * 192 + 98 + t] = nq[t] - tq[t]; }
    if (s == NPAST - 1) {
        const size_t pb = (size_t)b * 30 * 91;
        if (t < 3)  out[pb + t] = rvn[t];
        if (t < QD) out[pb + 3 + t] = nq[t];
        if (t < 4)  out[POSE_ELEMS + (size_t)b * 30 * 4 + t] = contn[t];
    } else if (!pastS) {
        const int k = s - NPAST + 1;
        const size_t pb = ((size_t)b * 30 + k) * 91;
        if (t < 3)  out[pb + t] = globn[t];
        if (t < QD) out[pb + 3 + t] = nq[t];
        if (t < 4)  out[POSE_ELEMS + ((size_t)b * 30 + k) * 4 + t] = contn[t];
    }
    if (s == NSTEPS - 1) return;

    const int nx = s + 1;
    if (nx < NPAST) {
        if (t < 4)  sv[t] = past_contacts[(b * NPAST + nx) * 4 + t];
        if (t < QD) { sv[4 + t] = past_quats[(b * NPAST + nx) * QD + t];
                      ov[3 + t] = past_quat_offset[(b * NPAST + nx) * QD + t]; }
        if (t < 3)  { sv[92 + t] = past_root_vel[(b * NPAST + nx) * 3 + t];
                      ov[t]      = past_root_offset[(b * NPAST + nx) * 3 + t]; }
    } else {
        if (t < 4)  sv[t] = contn[t];
        if (t < QD) { sv[4 + t] = nq[t]; ov[3 + t] = nq[t] - tq[t]; }
        if (t < 3)  { sv[92 + t] = rvn[t]; ov[t] = globn[t] - trp[t]; }
    }
    __syncthreads();
    {
        const int tt = t & 255, enc = t >> 8;
        const int c = tt & 127, sl = tt >> 7;
        const float* inp = enc ? ov : sv;
        const float* w1  = enc ? oe_w1 : se_w1;
        const int nin  = enc ? 91 : 95;
        const int half = enc ? 46 : 48;
        const int i0 = sl * half;
        const int iend = (i0 + half < nin) ? (i0 + half) : nin;
        float4 acc = {0.f, 0.f, 0.f, 0.f};
        #pragma unroll 8
        for (int k = 0; k < 48; ++k) {
            const int i = i0 + k;
            if (i < iend) fma4_(acc, inp[i], *(const float4*)(w1 + (size_t)i * 512 + 4 * c));
        }
        part4[enc * 256 + tt] = acc;
    }
    __syncthreads();
    if (t < 128) {
        const float4 a = part4[t], b2 = part4[128 + t];
        const float4 bb = *(const float4*)(se_b1 + 4 * t);
        float4 r; r.x = fmaxf(a.x + b2.x + bb.x, 0.f); r.y = fmaxf(a.y + b2.y + bb.y, 0.f);
        r.z = fmaxf(a.z + b2.z + bb.z, 0.f); r.w = fmaxf(a.w + b2.w + bb.w, 0.f);
        *(float4*)&bufA[4 * t] = r;
    } else if (t < 256) {
        const int c = t - 128;
        const float4 a = part4[256 + c], b2 = part4[384 + c];
        const float4 bb = *(const float4*)(oe_b1 + 4 * c);
        float4 r; r.x = fmaxf(a.x + b2.x + bb.x, 0.f); r.y = fmaxf(a.y + b2.y + bb.y, 0.f);
        r.z = fmaxf(a.z + b2.z + bb.z, 0.f); r.w = fmaxf(a.w + b2.w + bb.w, 0.f);
        *(float4*)&bufB[4 * c] = r;
    }
    __syncthreads();
    {
        const int tt = t & 255, enc = t >> 8;
        const int c = tt & 63, sl = tt >> 6;
        const float* inp = enc ? bufB : bufA;
        const float* w2  = enc ? oe_w2 : se_w2;
        float4 acc = {0.f, 0.f, 0.f, 0.f};
        const float* w = w2 + (size_t)(sl * 128) * 256 + 4 * c;
        #pragma unroll 8
        for (int k = 0; k < 128; ++k)
            fma4_(acc, inp[sl * 128 + k], *(const float4*)(w + (size_t)k * 256));
        part4[enc * 256 + tt] = acc;
    }
    __syncthreads();
    if (t < 64) {
        float4 v = part4[t];
        #pragma unroll
        for (int sl = 1; sl < 4; ++sl) { const float4 p = part4[sl * 64 + t];
            v.x += p.x; v.y += p.y; v.z += p.z; v.w += p.w; }
        const float4 bb = *(const float4*)(se_b2 + 4 * t);
        float4 r; r.x = fmaxf(v.x + bb.x, 0.f); r.y = fmaxf(v.y + bb.y, 0.f);
        r.z = fmaxf(v.z + bb.z, 0.f); r.w = fmaxf(v.w + bb.w, 0.f);
        *(float4*)(z_ws + b * ZDIM + 4 * t) = r;
    } else if (t < 128) {
        const int c = t - 64;
        float4 v = part4[256 + c];
        #pragma unroll
        for (int sl = 1; sl < 4; ++sl) { const float4 p = part4[256 + sl * 64 + c];
            v.x += p.x; v.y += p.y; v.z += p.z; v.w += p.w; }
        const float4 bb = *(const float4*)(oe_b2 + 4 * c);
        float4 r; r.x = fmaxf(v.x + bb.x, 0.f); r.y = fmaxf(v.y + bb.y, 0.f);
        r.z = fmaxf(v.z + bb.z, 0.f); r.w = fmaxf(v.w + bb.w, 0.f);
        *(float4*)(z_ws + b * ZDIM + 256 + 4 * c) = r;
    }
}

// ================= fp32 fallback path (ws too small) =================
__global__ void __launch_bounds__(256)
matvec_f32(const float* __restrict__ W, const float* __restrict__ z_ws,
           const float* __restrict__ pred_bias, float* __restrict__ g_ws)
{
    const int b = blockIdx.x >> 5, chunk = blockIdx.x & 31;
    const int wave = threadIdx.x >> 6, lane = threadIdx.x & 63;
    const int row0 = chunk * 64 + wave * 16;
    const float* zb = z_ws + b * ZDIM;
    const float biasv = (lane < 16) ? pred_bias[b * GDIM + row0 + lane] : 0.f;
    const int l4 = lane * 4;
    const float4 z0 = *(const float4*)(zb + l4);
    const float4 z1 = *(const float4*)(zb + 256 + l4);
    const float4 z2 = *(const float4*)(zb + 512 + l4);
    const float4 z3 = *(const float4*)(zb + 768 + l4);
    const float4 z4 = *(const float4*)(zb + 1024 + l4);
    const char* wb = (const char*)W + (size_t)b * GDIM * ZDIM * 4;

    #define ISSUE(p, B) { const char* a_ = wb + (size_t)(row0 + 2 * (p)) * (ZDIM * 4) + lane * 16; \
        _Pragma("unroll") for (int i = 0; i < 10; ++i) B[i] = *(const uint4*)(a_ + i * 1024); }

    uint4 bufa[10], bufb[10];
    ISSUE(0, bufa);
    #pragma unroll
    for (int p = 0; p < 8; ++p) {
        uint4* cur = (p & 1) ? bufb : bufa;
        uint4* nxt = (p & 1) ? bufa : bufb;
        if (p < 7) ISSUE(p + 1, nxt);
        float accA = 0.f, accB = 0.f;
        dot4_(cur[0], z0, accA); dot4_(cur[1], z1, accA); dot4_(cur[2], z2, accA);
        dot4_(cur[3], z3, accA); dot4_(cur[4], z4, accA);
        dot4_(cur[5], z0, accB); dot4_(cur[6], z1, accB); dot4_(cur[7], z2, accB);
        dot4_(cur[8], z3, accB); dot4_(cur[9], z4, accB);
        float s0 = accA + __shfl_xor(accA, 32);
        float s1 = accB + __shfl_xor(accB, 32);
        float u = (lane < 32) ? s0 : s1;
        #pragma unroll
        for (int m = 16; m >= 1; m >>= 1) u += __shfl_xor(u, m);
        const float badd = __shfl(biasv, 2 * p + ((lane >= 32) ? 1 : 0), 64);
        if (lane == 0)       g_ws[b * GDIM + row0 + 2 * p]     = u + badd;
        else if (lane == 32) g_ws[b * GDIM + row0 + 2 * p + 1] = u + badd;
    }
    #undef ISSUE
}

extern "C" void kernel_launch(void* const* d_in, const int* in_sizes, int n_in,
                              void* d_out, int out_size, void* d_ws, size_t ws_size,
                              hipStream_t stream) {
    const float* prv = (const float*)d_in[0];
    const float* pq  = (const float*)d_in[1];
    const float* pro = (const float*)d_in[2];
    const float* pqo = (const float*)d_in[3];
    const float* pc  = (const float*)d_in[4];
    const float* trp = (const float*)d_in[5];
    const float* tq  = (const float*)d_in[6];
    const float* irp = (const float*)d_in[7];
    const float* pw  = (const float*)d_in[8];
    const float* pb  = (const float*)d_in[9];
    const float* se_w1 = (const float*)d_in[10]; const float* se_b1 = (const float*)d_in[11];
    const float* se_w2 = (const float*)d_in[12]; const float* se_b2 = (const float*)d_in[13];
    const float* oe_w1 = (const float*)d_in[14]; const float* oe_b1 = (const float*)d_in[15];
    const float* oe_w2 = (const float*)d_in[16]; const float* oe_b2 = (const float*)d_in[17];
    const float* te_w1 = (const float*)d_in[18]; const float* te_b1 = (const float*)d_in[19];
    const float* te_w2 = (const float*)d_in[20]; const float* te_b2 = (const float*)d_in[21];
    const float* de_w1 = (const float*)d_in[22]; const float* de_b1 = (const float*)d_in[23];
    const float* de_w2 = (const float*)d_in[24]; const float* de_b2 = (const float*)d_in[25];
    const float* de_w3 = (const float*)d_in[26]; const float* de_b3 = (const float*)d_in[27];
    float* outp = (float*)d_out;

    const size_t WB2  = (size_t)BATCH * GDIM * DYNC * 2;   // bf16 dynamic weights
    const size_t AUXB = (size_t)BATCH * (GDIM + ZDIM + GDIM + HDIM + 192) * 4;
    const bool bf = ws_size >= WB2 + AUXB;

    char* base = (char*)d_ws;
    float* g0_ws; float* z_ws;
    if (bf) {
        g0_ws  = (float*)(base + WB2);
        z_ws   = g0_ws + (size_t)BATCH * GDIM;
    } else {
        g0_ws  = nullptr;
        z_ws   = (float*)base;
    }
    float* g_ws   = z_ws + (size_t)BATCH * ZDIM;
    float* c_ws   = g_ws + (size_t)BATCH * GDIM;
    float* car_ws = c_ws + (size_t)BATCH * HDIM;

    initk<<<dim3(BATCH), dim3(512), 0, stream>>>(prv, pq, pro, pqo, pc, tq, irp,
        se_w1, se_b1, se_w2, se_b2, oe_w1, oe_b1, oe_w2, oe_b2,
        te_w1, te_b1, te_w2, te_b2, z_ws, c_ws, car_ws);

    if (bf) {
        for (int s = 0; s < NSTEPS; ++s) {
            if (s == 0) {
                // step-0 GEMV over fp32 weights, fused with bf16 conversion + static fold
                matvec0_conv<<<dim3(BATCH * 32), dim3(256), 0, stream>>>(
                    pw, z_ws, pb, (unsigned short*)d_ws, g_ws, g0_ws);
            } else {
                matvec2_bf16<<<dim3(BATCH * 32), dim3(256), 0, stream>>>(
                    (const unsigned short*)d_ws, z_ws, g0_ws, g_ws);
            }
            stepk<<<dim3(BATCH), dim3(512), 0, stream>>>(prv, pq, pro, pqo, pc, trp, tq,
                se_w1, se_b1, se_w2, se_b2, oe_w1, oe_b1, oe_w2, oe_b2,
                de_w1, de_b1, de_w2, de_b2, de_w3, de_b3,
                outp, z_ws, g_ws, c_ws, car_ws, s);
        }
    } else {
        for (int s = 0; s < NSTEPS; ++s) {
            matvec_f32<<<dim3(BATCH * 32), dim3(256), 0, stream>>>(pw, z_ws, pb, g_ws);
            stepk<<<dim3(BATCH), dim3(512), 0, stream>>>(prv, pq, pro, pqo, pc, trp, tq,
                se_w1, se_b1, se_w2, se_b2, oe_w1, oe_b1, oe_w2, oe_b2,
                de_w1, de_b1, de_w2, de_b2, de_w3, de_b3,
                outp, z_ws, g_ws, c_ws, car_ws, s);
        }
    }
}

// Round 9
// 4984.139 us; speedup vs baseline: 9.2281x; 1.0782x over previous
//
#include <hip/hip_runtime.h>
#include <hip/hip_bf16.h>
#include <math.h>

#define BATCH 128
#define QD 88
#define HDIM 512
#define ZDIM 1280
#define GDIM 2048
#define DYNC 1024          // dynamic cols after folding static h_target block
#define NPAST 10
#define NTRANS 29
#define NSTEPS (NPAST + NTRANS)
#define OUTD 95
#define POSE_ELEMS (BATCH * 30 * 91)

typedef float f32x4 __attribute__((ext_vector_type(4)));
typedef unsigned int u32x4 __attribute__((ext_vector_type(4)));
typedef unsigned int u32x2 __attribute__((ext_vector_type(2)));

__device__ __forceinline__ float sig_(float x) { return 1.0f / (1.0f + expf(-x)); }
__device__ __forceinline__ float bflo_(unsigned u) { return __uint_as_float(u << 16); }
__device__ __forceinline__ float bfhi_(unsigned u) { return __uint_as_float(u & 0xffff0000u); }
__device__ __forceinline__ unsigned bfrne_(float f) {
    return (__float_as_uint(f) + 0x7fffu + ((__float_as_uint(f) >> 16) & 1u)) >> 16;
}
__device__ __forceinline__ void dot8_(const u32x4 wv, const float4 za, const float4 zb,
                                      float& d) {
    d = fmaf(bflo_(wv.x), za.x, d); d = fmaf(bfhi_(wv.x), za.y, d);
    d = fmaf(bflo_(wv.y), za.z, d); d = fmaf(bfhi_(wv.y), za.w, d);
    d = fmaf(bflo_(wv.z), zb.x, d); d = fmaf(bfhi_(wv.z), zb.y, d);
    d = fmaf(bflo_(wv.w), zb.z, d); d = fmaf(bfhi_(wv.w), zb.w, d);
}
__device__ __forceinline__ void dot8u_(const uint4 wv, const float4 za, const float4 zb,
                                       float& d) {
    d = fmaf(bflo_(wv.x), za.x, d); d = fmaf(bfhi_(wv.x), za.y, d);
    d = fmaf(bflo_(wv.y), za.z, d); d = fmaf(bfhi_(wv.y), za.w, d);
    d = fmaf(bflo_(wv.z), zb.x, d); d = fmaf(bfhi_(wv.z), zb.y, d);
    d = fmaf(bflo_(wv.w), zb.z, d); d = fmaf(bfhi_(wv.w), zb.w, d);
}
__device__ __forceinline__ void dot4_(const uint4 wv, const float4 zv, float& d) {
    const float4 f = *(const float4*)&wv;
    d = fmaf(f.x, zv.x, d); d = fmaf(f.y, zv.y, d);
    d = fmaf(f.z, zv.z, d); d = fmaf(f.w, zv.w, d);
}
__device__ __forceinline__ void fma4_(float4& acc, float x, const float4 w) {
    acc.x = fmaf(x, w.x, acc.x); acc.y = fmaf(x, w.y, acc.y);
    acc.z = fmaf(x, w.z, acc.z); acc.w = fmaf(x, w.w, acc.w);
}
__device__ __forceinline__ u32x2 pk2_(const uint4 v) {
    u32x2 o;
    o.x = bfrne_(__uint_as_float(v.x)) | (bfrne_(__uint_as_float(v.y)) << 16);
    o.y = bfrne_(__uint_as_float(v.z)) | (bfrne_(__uint_as_float(v.w)) << 16);
    return o;
}
__device__ __forceinline__ void unpk8_(const uint4 v, float* w) {
    w[0] = bflo_(v.x); w[1] = bfhi_(v.x); w[2] = bflo_(v.y); w[3] = bfhi_(v.y);
    w[4] = bflo_(v.z); w[5] = bfhi_(v.z); w[6] = bflo_(v.w); w[7] = bfhi_(v.w);
}
__device__ __forceinline__ float dote_(const float* w, const float4 a, const float4 b) {
    float d = 0.f;
    d = fmaf(w[0], a.x, d); d = fmaf(w[1], a.y, d); d = fmaf(w[2], a.z, d); d = fmaf(w[3], a.w, d);
    d = fmaf(w[4], b.x, d); d = fmaf(w[5], b.y, d); d = fmaf(w[6], b.z, d); d = fmaf(w[7], b.w, d);
    return d;
}

// ---- step-0 GEMV over fp32 weights, fused with bf16 conversion + static fold ----
__global__ void __launch_bounds__(256)
matvec0_conv(const float* __restrict__ W, const float* __restrict__ z_ws,
             const float* __restrict__ pred_bias, unsigned short* __restrict__ Wd,
             float* __restrict__ g_ws, float* __restrict__ g0_ws)
{
    const int b = blockIdx.x >> 5, chunk = blockIdx.x & 31;
    const int wave = threadIdx.x >> 6, lane = threadIdx.x & 63;
    const int row0 = chunk * 64 + wave * 16;
    const float* zb = z_ws + b * ZDIM;
    const float biasv = (lane < 16) ? pred_bias[b * GDIM + row0 + lane] : 0.f;
    const int l4 = lane * 4;
    const float4 z0 = *(const float4*)(zb + l4);
    const float4 z1 = *(const float4*)(zb + 256 + l4);
    const float4 zh = *(const float4*)(zb + 512 + l4);
    const float4 z3 = *(const float4*)(zb + 768 + l4);
    const float4 z4 = *(const float4*)(zb + 1024 + l4);
    const char* wb = (const char*)W + (size_t)b * GDIM * ZDIM * 4;
    char* dstB = (char*)(Wd + (size_t)b * GDIM * DYNC);

    #define ISSUE(p, B) { const char* a_ = wb + (size_t)(row0 + 2 * (p)) * (ZDIM * 4) + lane * 16; \
        _Pragma("unroll") for (int i = 0; i < 10; ++i) B[i] = *(const uint4*)(a_ + i * 1024); }

    uint4 bufa[10], bufb[10];
    ISSUE(0, bufa);
    #pragma unroll
    for (int p = 0; p < 8; ++p) {
        uint4* cur = (p & 1) ? bufb : bufa;
        uint4* nxt = (p & 1) ? bufa : bufb;
        if (p < 7) ISSUE(p + 1, nxt);
        float dynA = 0.f, dynB = 0.f, statA = 0.f, statB = 0.f;
        dot4_(cur[0], z0, dynA); dot4_(cur[1], z1, dynA);
        dot4_(cur[2], zh, statA);
        dot4_(cur[3], z3, dynA); dot4_(cur[4], z4, dynA);
        dot4_(cur[5], z0, dynB); dot4_(cur[6], z1, dynB);
        dot4_(cur[7], zh, statB);
        dot4_(cur[8], z3, dynB); dot4_(cur[9], z4, dynB);
        {
            char* rd = dstB + (size_t)(row0 + 2 * p) * (DYNC * 2) + 8 * lane;
            __builtin_nontemporal_store(pk2_(cur[0]), (u32x2*)(rd));
            __builtin_nontemporal_store(pk2_(cur[1]), (u32x2*)(rd + 512));
            __builtin_nontemporal_store(pk2_(cur[3]), (u32x2*)(rd + 1024));
            __builtin_nontemporal_store(pk2_(cur[4]), (u32x2*)(rd + 1536));
            char* rd2 = rd + (DYNC * 2);
            __builtin_nontemporal_store(pk2_(cur[5]), (u32x2*)(rd2));
            __builtin_nontemporal_store(pk2_(cur[6]), (u32x2*)(rd2 + 512));
            __builtin_nontemporal_store(pk2_(cur[8]), (u32x2*)(rd2 + 1024));
            __builtin_nontemporal_store(pk2_(cur[9]), (u32x2*)(rd2 + 1536));
        }
        float sd0 = dynA + __shfl_xor(dynA, 32);
        float sd1 = dynB + __shfl_xor(dynB, 32);
        float ud = (lane < 32) ? sd0 : sd1;
        float ss0 = statA + __shfl_xor(statA, 32);
        float ss1 = statB + __shfl_xor(statB, 32);
        float us = (lane < 32) ? ss0 : ss1;
        #pragma unroll
        for (int m = 16; m >= 1; m >>= 1) { ud += __shfl_xor(ud, m); us += __shfl_xor(us, m); }
        const float badd = __shfl(biasv, 2 * p + ((lane >= 32) ? 1 : 0), 64);
        if (lane == 0 || lane == 32) {
            const int r = row0 + 2 * p + ((lane >= 32) ? 1 : 0);
            g0_ws[b * GDIM + r] = us + badd;
            g_ws[b * GDIM + r]  = ud + us + badd;
        }
    }
    #undef ISSUE
}

// ---- E-pass: E[s][b][row] = g0[b][row] + W_so_bf16[row] . enc9[s][b]  (s = 1..9 -> idx 0..8)
// grid 4096 = 128 x 32 chunks; block 256 = 4 waves; wave: 16 rows (8 pairs).
// Per-lane enc fragments (9 steps x 8 cols) live in registers, reused across all rows.
__global__ void __launch_bounds__(256)
epass(const unsigned short* __restrict__ Wd, const float* __restrict__ enc9,
      const float* __restrict__ g0_ws, float* __restrict__ E_ws)
{
    const int b = blockIdx.x >> 5, chunk = blockIdx.x & 31;
    const int wave = threadIdx.x >> 6, lane = threadIdx.x & 63;
    const int row0 = chunk * 64 + wave * 16;
    float4 eA[9], eB[9];
    #pragma unroll
    for (int s = 0; s < 9; ++s) {
        const float* eb = enc9 + ((size_t)s * BATCH + b) * 512 + lane * 8;
        eA[s] = *(const float4*)(eb); eB[s] = *(const float4*)(eb + 4);
    }
    const float g0v = (lane < 16) ? g0_ws[b * GDIM + row0 + lane] : 0.f;
    const char* wb = (const char*)Wd + (size_t)b * GDIM * DYNC * 2;

    #define ISSUE(p, B) { const char* a_ = wb + (size_t)(row0 + 2 * (p)) * (DYNC * 2) + lane * 16; \
        B[0] = __builtin_nontemporal_load((const u32x4*)(a_)); \
        B[1] = __builtin_nontemporal_load((const u32x4*)(a_ + 2048)); }

    u32x4 bufa[2], bufb[2];
    ISSUE(0, bufa);
    #pragma unroll
    for (int p = 0; p < 8; ++p) {
        u32x4* cur = (p & 1) ? bufb : bufa;
        u32x4* nxt = (p & 1) ? bufa : bufb;
        if (p < 7) ISSUE(p + 1, nxt);
        float w0[8], w1[8];
        unpk8_(*(const uint4*)&cur[0], w0);
        unpk8_(*(const uint4*)&cur[1], w1);
        const float badd = __shfl(g0v, 2 * p + ((lane >= 32) ? 1 : 0), 64);
        #pragma unroll
        for (int s = 0; s < 9; ++s) {
            const float aA = dote_(w0, eA[s], eB[s]);
            const float aB = dote_(w1, eA[s], eB[s]);
            const float s0 = aA + __shfl_xor(aA, 32);
            const float s1 = aB + __shfl_xor(aB, 32);
            float u = (lane < 32) ? s0 : s1;
            #pragma unroll
            for (int m = 16; m >= 1; m >>= 1) u += __shfl_xor(u, m);
            if (lane == 0)
                E_ws[((size_t)s * BATCH + b) * GDIM + row0 + 2 * p] = u + badd;
            else if (lane == 32)
                E_ws[((size_t)s * BATCH + b) * GDIM + row0 + 2 * p + 1] = u + badd;
        }
    }
    #undef ISSUE
}

// ---- past-step GEMV (s=1..9): gates = E[s] + Wh . h   (streams only the 512 h-cols) ----
__global__ void __launch_bounds__(256)
matvecH(const unsigned short* __restrict__ Wd, const float* __restrict__ z_ws,
        const float* __restrict__ Es, float* __restrict__ g_ws)
{
    const int b = blockIdx.x >> 5, chunk = blockIdx.x & 31;
    const int wave = threadIdx.x >> 6, lane = threadIdx.x & 63;
    const int row0 = chunk * 64 + wave * 16;
    const float* zb = z_ws + b * ZDIM;
    const int l8 = lane * 8;
    const float4 qA = *(const float4*)(zb + 768 + l8), qB = *(const float4*)(zb + 768 + l8 + 4);
    const float Ev = (lane < 16) ? Es[b * GDIM + row0 + lane] : 0.f;
    const char* wb = (const char*)Wd + (size_t)b * GDIM * DYNC * 2;

    // h-cols live at byte offset [1024, 2048) of each 2048-B row; normal loads (L3 reuse).
    #define ISSUE(p, B) { const char* a_ = wb + (size_t)(row0 + 2 * (p)) * (DYNC * 2) + 1024 + lane * 16; \
        B[0] = *(const u32x4*)(a_); B[1] = *(const u32x4*)(a_ + 2048); }

    u32x4 buf0[2], buf1[2], buf2[2];
    ISSUE(0, buf0);
    ISSUE(1, buf1);
    #pragma unroll
    for (int p = 0; p < 8; ++p) {
        u32x4* cur = (p % 3 == 0) ? buf0 : (p % 3 == 1) ? buf1 : buf2;
        u32x4* nxt = ((p + 2) % 3 == 0) ? buf0 : ((p + 2) % 3 == 1) ? buf1 : buf2;
        if (p < 6) ISSUE(p + 2, nxt);
        float accA = 0.f, accB = 0.f;
        dot8_(cur[0], qA, qB, accA);
        dot8_(cur[1], qA, qB, accB);
        float s0 = accA + __shfl_xor(accA, 32);
        float s1 = accB + __shfl_xor(accB, 32);
        float u = (lane < 32) ? s0 : s1;
        #pragma unroll
        for (int m = 16; m >= 1; m >>= 1) u += __shfl_xor(u, m);
        const float badd = __shfl(Ev, 2 * p + ((lane >= 32) ? 1 : 0), 64);
        if (lane == 0)       g_ws[b * GDIM + row0 + 2 * p]     = u + badd;
        else if (lane == 32) g_ws[b * GDIM + row0 + 2 * p + 1] = u + badd;
    }
    #undef ISSUE
}

// ---- transition-step GEMV over folded bf16 weights (full 1024 dyn cols) ----
__global__ void __launch_bounds__(256)
matvec2_bf16(const unsigned short* __restrict__ W, const float* __restrict__ z_ws,
             const float* __restrict__ g0_ws, float* __restrict__ g_ws)
{
    const int b = blockIdx.x >> 5, chunk = blockIdx.x & 31;
    const int wave = threadIdx.x >> 6, lane = threadIdx.x & 63;
    const int row0 = chunk * 64 + wave * 16;
    const float* zb = z_ws + b * ZDIM;
    const int l8 = lane * 8;
    const float4 pA = *(const float4*)(zb + l8),       pB = *(const float4*)(zb + l8 + 4);
    const float4 qA = *(const float4*)(zb + 768 + l8), qB = *(const float4*)(zb + 768 + l8 + 4);
    const float g0v = (lane < 16) ? g0_ws[b * GDIM + row0 + lane] : 0.f;
    const char* wb = (const char*)W + (size_t)b * GDIM * DYNC * 2;

    #define ISSUE(p, B) { const char* a_ = wb + (size_t)(row0 + 2 * (p)) * (DYNC * 2) + lane * 16; \
        B[0] = __builtin_nontemporal_load((const u32x4*)(a_)); \
        B[1] = __builtin_nontemporal_load((const u32x4*)(a_ + 1024)); \
        B[2] = __builtin_nontemporal_load((const u32x4*)(a_ + 2048)); \
        B[3] = __builtin_nontemporal_load((const u32x4*)(a_ + 3072)); }

    u32x4 buf0[4], buf1[4], buf2[4];
    ISSUE(0, buf0);
    ISSUE(1, buf1);
    #pragma unroll
    for (int p = 0; p < 8; ++p) {
        u32x4* cur = (p % 3 == 0) ? buf0 : (p % 3 == 1) ? buf1 : buf2;
        u32x4* nxt = ((p + 2) % 3 == 0) ? buf0 : ((p + 2) % 3 == 1) ? buf1 : buf2;
        if (p < 6) ISSUE(p + 2, nxt);
        float accA = 0.f, accB = 0.f;
        dot8_(cur[0], pA, pB, accA); dot8_(cur[1], qA, qB, accA);
        dot8_(cur[2], pA, pB, accB); dot8_(cur[3], qA, qB, accB);
        float s0 = accA + __shfl_xor(accA, 32);
        float s1 = accB + __shfl_xor(accB, 32);
        float u = (lane < 32) ? s0 : s1;
        #pragma unroll
        for (int m = 16; m >= 1; m >>= 1) u += __shfl_xor(u, m);
        const float badd = __shfl(g0v, 2 * p + ((lane >= 32) ? 1 : 0), 64);
        if (lane == 0)       g_ws[b * GDIM + row0 + 2 * p]     = u + badd;
        else if (lane == 32) g_ws[b * GDIM + row0 + 2 * p + 1] = u + badd;
    }
    #undef ISSUE
}

// ---------------- init: state=0, h_target, step-0 encoders ----------------
__global__ void __launch_bounds__(512)
initk(const float* __restrict__ past_root_vel, const float* __restrict__ past_quats,
      const float* __restrict__ past_root_offset, const float* __restrict__ past_quat_offset,
      const float* __restrict__ past_contacts, const float* __restrict__ target_quats,
      const float* __restrict__ init_root_pos,
      const float* __restrict__ se_w1, const float* __restrict__ se_b1,
      const float* __restrict__ se_w2, const float* __restrict__ se_b2,
      const float* __restrict__ oe_w1, const float* __restrict__ oe_b1,
      const float* __restrict__ oe_w2, const float* __restrict__ oe_b2,
      const float* __restrict__ te_w1, const float* __restrict__ te_b1,
      const float* __restrict__ te_w2, const float* __restrict__ te_b2,
      float* __restrict__ z_ws, float* __restrict__ c_ws, float* __restrict__ car_ws)
{
    const int b = blockIdx.x, t = threadIdx.x;
    __shared__ float tq[QD], bufA[512], bufB[512], sv[95], ov[91];

    if (t < 192) car_ws[b * 192 + t] = (t < 3) ? init_root_pos[b * 3 + t] : 0.f;
    c_ws[b * HDIM + t] = 0.f;
    z_ws[b * ZDIM + 768 + t] = 0.f;
    if (t < QD) tq[t] = target_quats[b * QD + t];
    if (t < 4)  sv[t] = past_contacts[b * NPAST * 4 + t];
    if (t < QD) { sv[4 + t] = past_quats[b * NPAST * QD + t];
                  ov[3 + t] = past_quat_offset[b * NPAST * QD + t]; }
    if (t < 3)  { sv[92 + t] = past_root_vel[b * NPAST * 3 + t];
                  ov[t]      = past_root_offset[b * NPAST * 3 + t]; }
    __syncthreads();
    {
        float a = te_b1[t];
        #pragma unroll 8
        for (int i = 0; i < QD; ++i) a = fmaf(tq[i], te_w1[i * 512 + t], a);
        bufA[t] = fmaxf(a, 0.f);
    }
    __syncthreads();
    if (t < 256) {
        float a = te_b2[t];
        #pragma unroll 8
        for (int i = 0; i < 512; ++i) a = fmaf(bufA[i], te_w2[i * 256 + t], a);
        z_ws[b * ZDIM + 512 + t] = fmaxf(a, 0.f);
    }
    __syncthreads();
    {
        float aS = se_b1[t], aO = oe_b1[t];
        #pragma unroll 8
        for (int i = 0; i < 91; ++i) { aS = fmaf(sv[i], se_w1[i * 512 + t], aS);
                                       aO = fmaf(ov[i], oe_w1[i * 512 + t], aO); }
        #pragma unroll
        for (int i = 91; i < 95; ++i) aS = fmaf(sv[i], se_w1[i * 512 + t], aS);
        bufA[t] = fmaxf(aS, 0.f);
        bufB[t] = fmaxf(aO, 0.f);
    }
    __syncthreads();
    if (t < 256) {
        float a = se_b2[t];
        #pragma unroll 8
        for (int i = 0; i < 512; ++i) a = fmaf(bufA[i], se_w2[i * 256 + t], a);
        z_ws[b * ZDIM + t] = fmaxf(a, 0.f);
    } else {
        const int j = t - 256;
        float a = oe_b2[j];
        #pragma unroll 8
        for (int i = 0; i < 512; ++i) a = fmaf(bufB[i], oe_w2[i * 256 + j], a);
        z_ws[b * ZDIM + 256 + j] = fmaxf(a, 0.f);
    }
}

// ---- batch-encode past steps 1..9 -> enc9[(s-1)*BATCH + b][512] ([h_state | h_off]) ----
__global__ void __launch_bounds__(512)
enc_past(const float* __restrict__ past_root_vel, const float* __restrict__ past_quats,
         const float* __restrict__ past_root_offset, const float* __restrict__ past_quat_offset,
         const float* __restrict__ past_contacts,
         const float* __restrict__ se_w1, const float* __restrict__ se_b1,
         const float* __restrict__ se_w2, const float* __restrict__ se_b2,
         const float* __restrict__ oe_w1, const float* __restrict__ oe_b1,
         const float* __restrict__ oe_w2, const float* __restrict__ oe_b2,
         float* __restrict__ enc9)
{
    const int b = blockIdx.x, t = threadIdx.x;
    const int s = blockIdx.y + 1;               // past step 1..9
    __shared__ float bufA[512], bufB[512], sv[95], ov[91];

    if (t < 4)  sv[t] = past_contacts[(b * NPAST + s) * 4 + t];
    if (t < QD) { sv[4 + t] = past_quats[(b * NPAST + s) * QD + t];
                  ov[3 + t] = past_quat_offset[(b * NPAST + s) * QD + t]; }
    if (t < 3)  { sv[92 + t] = past_root_vel[(b * NPAST + s) * 3 + t];
                  ov[t]      = past_root_offset[(b * NPAST + s) * 3 + t]; }
    __syncthreads();
    {
        float aS = se_b1[t], aO = oe_b1[t];
        #pragma unroll 8
        for (int i = 0; i < 91; ++i) { aS = fmaf(sv[i], se_w1[i * 512 + t], aS);
                                       aO = fmaf(ov[i], oe_w1[i * 512 + t], aO); }
        #pragma unroll
        for (int i = 91; i < 95; ++i) aS = fmaf(sv[i], se_w1[i * 512 + t], aS);
        bufA[t] = fmaxf(aS, 0.f);
        bufB[t] = fmaxf(aO, 0.f);
    }
    __syncthreads();
    float* dst = enc9 + ((size_t)(s - 1) * BATCH + b) * 512;
    if (t < 256) {
        float a = se_b2[t];
        #pragma unroll 8
        for (int i = 0; i < 512; ++i) a = fmaf(bufA[i], se_w2[i * 256 + t], a);
        dst[t] = fmaxf(a, 0.f);
    } else {
        const int j = t - 256;
        float a = oe_b2[j];
        #pragma unroll 8
        for (int i = 0; i < 512; ++i) a = fmaf(bufB[i], oe_w2[i * 256 + j], a);
        dst[256 + j] = fmaxf(a, 0.f);
    }
}

// ---------------- per-step: LSTM + decoder + state update + next encoders ----------------
__global__ void __launch_bounds__(512)
stepk(const float* __restrict__ past_root_vel, const float* __restrict__ past_quats,
      const float* __restrict__ past_root_offset, const float* __restrict__ past_quat_offset,
      const float* __restrict__ past_contacts, const float* __restrict__ target_root_pos,
      const float* __restrict__ target_quats,
      const float* __restrict__ se_w1, const float* __restrict__ se_b1,
      const float* __restrict__ se_w2, const float* __restrict__ se_b2,
      const float* __restrict__ oe_w1, const float* __restrict__ oe_b1,
      const float* __restrict__ oe_w2, const float* __restrict__ oe_b2,
      const float* __restrict__ de_w1, const float* __restrict__ de_b1,
      const float* __restrict__ de_w2, const float* __restrict__ de_b2,
      const float* __restrict__ de_w3, const float* __restrict__ de_b3,
      float* __restrict__ out, float* __restrict__ z_ws, const float* __restrict__ g_ws,
      float* __restrict__ c_ws, float* __restrict__ car_ws, int s, int skip_enc)
{
    const int b = blockIdx.x, t = threadIdx.x;
    __shared__ float4 part4[512];
    __shared__ __align__(16) float h2s[HDIM], bufA[512], bufB[512], d2[256];
    __shared__ float outv[OUTD], nq[QD], sv[95], ov[91], carryL[192], tq[QD], trp[3];
    __shared__ float rvn[3], globn[3], contn[4];

    if (t < 192) carryL[t] = car_ws[b * 192 + t];
    if (t < QD) tq[t] = target_quats[b * QD + t];
    if (t < 3)  trp[t] = target_root_pos[b * 3 + t];

    // LSTM (gates already include bias + static h_target fold)
    {
        const float* g = g_ws + b * GDIM;
        const float ig = g[t], fg = g[512 + t], gg = g[1024 + t], og = g[1536 + t];
        const float c2 = sig_(fg) * c_ws[b * HDIM + t] + sig_(ig) * tanhf(gg);
        c_ws[b * HDIM + t] = c2;
        const float h2 = sig_(og) * tanhf(c2);
        h2s[t] = h2;
        z_ws[b * ZDIM + 768 + t] = h2;
    }
    __syncthreads();
    // decoder L1: 512 -> 512
    {
        const int c = t & 127, s4 = t >> 7;
        float4 acc = {0.f, 0.f, 0.f, 0.f};
        const float* w = de_w1 + (size_t)(s4 * 128) * 512 + 4 * c;
        #pragma unroll 8
        for (int k = 0; k < 128; ++k)
            fma4_(acc, h2s[s4 * 128 + k], *(const float4*)(w + (size_t)k * 512));
        part4[t] = acc;
    }
    __syncthreads();
    if (t < 128) {
        float4 v = part4[t];
        #pragma unroll
        for (int s4 = 1; s4 < 4; ++s4) { const float4 p = part4[s4 * 128 + t];
            v.x += p.x; v.y += p.y; v.z += p.z; v.w += p.w; }
        const float4 bb = *(const float4*)(de_b1 + 4 * t);
        float4 r; r.x = fmaxf(v.x + bb.x, 0.f); r.y = fmaxf(v.y + bb.y, 0.f);
        r.z = fmaxf(v.z + bb.z, 0.f); r.w = fmaxf(v.w + bb.w, 0.f);
        *(float4*)&bufA[4 * t] = r;
    }
    __syncthreads();
    // decoder L2: 512 -> 256
    {
        const int c = t & 63, s8 = t >> 6;
        float4 acc = {0.f, 0.f, 0.f, 0.f};
        const float* w = de_w2 + (size_t)(s8 * 64) * 256 + 4 * c;
        #pragma unroll 8
        for (int k = 0; k < 64; ++k)
            fma4_(acc, bufA[s8 * 64 + k], *(const float4*)(w + (size_t)k * 256));
        part4[t] = acc;
    }
    __syncthreads();
    if (t < 64) {
        float4 v = part4[t];
        #pragma unroll
        for (int s8 = 1; s8 < 8; ++s8) { const float4 p = part4[s8 * 64 + t];
            v.x += p.x; v.y += p.y; v.z += p.z; v.w += p.w; }
        const float4 bb = *(const float4*)(de_b2 + 4 * t);
        float4 r; r.x = fmaxf(v.x + bb.x, 0.f); r.y = fmaxf(v.y + bb.y, 0.f);
        r.z = fmaxf(v.z + bb.z, 0.f); r.w = fmaxf(v.w + bb.w, 0.f);
        *(float4*)&d2[4 * t] = r;
    }
    __syncthreads();
    // decoder L3: 256 -> 95
    if (t < OUTD) {
        float acc = de_b3[t];
        #pragma unroll 16
        for (int i = 0; i < 256; ++i) acc = fmaf(d2[i], de_w3[i * OUTD + t], acc);
        outv[t] = acc;
    }
    __syncthreads();

    const bool pastS = (s < NPAST);
    if (t < QD) {
        const float qin = pastS ? past_quats[(b * NPAST + s) * QD + t] : carryL[10 + t];
        nq[t] = outv[t] + qin;
    }
    __syncthreads();
    if (t < 22) {
        const float a = nq[4 * t], b2 = nq[4 * t + 1], c3 = nq[4 * t + 2], d4 = nq[4 * t + 3];
        const float inv = 1.f / fmaxf(sqrtf(a * a + b2 * b2 + c3 * c3 + d4 * d4), 1e-12f);
        nq[4 * t] = a * inv; nq[4 * t + 1] = b2 * inv; nq[4 * t + 2] = c3 * inv; nq[4 * t + 3] = d4 * inv;
    }
    if (t < 3) {
        const float rin = pastS ? past_root_vel[(b * NPAST + s) * 3 + t] : carryL[3 + t];
        const float nrv = outv[88 + t] + rin;
        const float g = carryL[t] + (pastS ? rin : nrv);
        rvn[t] = nrv; globn[t] = g;
    }
    if (t < 4) contn[t] = sig_(outv[91 + t]);
    __syncthreads();

    if (t < 3) { car_ws[b * 192 + t] = globn[t]; car_ws[b * 192 + 3 + t] = rvn[t];
                 car_ws[b * 192 + 186 + t] = globn[t] - trp[t]; }
    if (t < 4) car_ws[b * 192 + 6 + t] = contn[t];
    if (t < QD) { car_ws[b * 192 + 10 + t] = nq[t]; car_ws[b * 192 + 98 + t] = nq[t] - tq[t]; }
    if (s == NPAST - 1) {
        const size_t pb = (size_t)b * 30 * 91;
        if (t < 3)  out[pb + t] = rvn[t];
        if (t < QD) out[pb + 3 + t] = nq[t];
        if (t < 4)  out[POSE_ELEMS + (size_t)b * 30 * 4 + t] = contn[t];
    } else if (!pastS) {
        const int k = s - NPAST + 1;
        const size_t pb = ((size_t)b * 30 + k) * 91;
        if (t < 3)  out[pb + t] = globn[t];
        if (t < QD) out[pb + 3 + t] = nq[t];
        if (t < 4)  out[POSE_ELEMS + ((size_t)b * 30 + k) * 4 + t] = contn[t];
    }
    if (s == NSTEPS - 1) return;
    if (skip_enc) return;     // next step is a past step with precomputed encodings

    const int nx = s + 1;
    if (nx < NPAST) {
        if (t < 4)  sv[t] = past_contacts[(b * NPAST + nx) * 4 + t];
        if (t < QD) { sv[4 + t] = past_quats[(b * NPAST + nx) * QD + t];
                      ov[3 + t] = past_quat_offset[(b * NPAST + nx) * QD + t]; }
        if (t < 3)  { sv[92 + t] = past_root_vel[(b * NPAST + nx) * 3 + t];
                      ov[t]      = past_root_offset[(b * NPAST + nx) * 3 + t]; }
    } else {
        if (t < 4)  sv[t] = contn[t];
        if (t < QD) { sv[4 + t] = nq[t]; ov[3 + t] = nq[t] - tq[t]; }
        if (t < 3)  { sv[92 + t] = rvn[t]; ov[t] = globn[t] - trp[t]; }
    }
    __syncthreads();
    {
        const int tt = t & 255, enc = t >> 8;
        const int c = tt & 127, sl = tt >> 7;
        const float* inp = enc ? ov : sv;
        const float* w1  = enc ? oe_w1 : se_w1;
        const int nin  = enc ? 91 : 95;
        const int half = enc ? 46 : 48;
        const int i0 = sl * half;
        const int iend = (i0 + half < nin) ? (i0 + half) : nin;
        float4 acc = {0.f, 0.f, 0.f, 0.f};
        #pragma unroll 8
        for (int k = 0; k < 48; ++k) {
            const int i = i0 + k;
            if (i < iend) fma4_(acc, inp[i], *(const float4*)(w1 + (size_t)i * 512 + 4 * c));
        }
        part4[enc * 256 + tt] = acc;
    }
    __syncthreads();
    if (t < 128) {
        const float4 a = part4[t], b2 = part4[128 + t];
        const float4 bb = *(const float4*)(se_b1 + 4 * t);
        float4 r; r.x = fmaxf(a.x + b2.x + bb.x, 0.f); r.y = fmaxf(a.y + b2.y + bb.y, 0.f);
        r.z = fmaxf(a.z + b2.z + bb.z, 0.f); r.w = fmaxf(a.w + b2.w + bb.w, 0.f);
        *(float4*)&bufA[4 * t] = r;
    } else if (t < 256) {
        const int c = t - 128;
        const float4 a = part4[256 + c], b2 = part4[384 + c];
        const float4 bb = *(const float4*)(oe_b1 + 4 * c);
        float4 r; r.x = fmaxf(a.x + b2.x + bb.x, 0.f); r.y = fmaxf(a.y + b2.y + bb.y, 0.f);
        r.z = fmaxf(a.z + b2.z + bb.z, 0.f); r.w = fmaxf(a.w + b2.w + bb.w, 0.f);
        *(float4*)&bufB[4 * c] = r;
    }
    __syncthreads();
    {
        const int tt = t & 255, enc = t >> 8;
        const int c = tt & 63, sl = tt >> 6;
        const float* inp = enc ? bufB : bufA;
        const float* w2  = enc ? oe_w2 : se_w2;
        float4 acc = {0.f, 0.f, 0.f, 0.f};
        const float* w = w2 + (size_t)(sl * 128) * 256 + 4 * c;
        #pragma unroll 8
        for (int k = 0; k < 128; ++k)
            fma4_(acc, inp[sl * 128 + k], *(const float4*)(w + (size_t)k * 256));
        part4[enc * 256 + tt] = acc;
    }
    __syncthreads();
    if (t < 64) {
        float4 v = part4[t];
        #pragma unroll
        for (int sl = 1; sl < 4; ++sl) { const float4 p = part4[sl * 64 + t];
            v.x += p.x; v.y += p.y; v.z += p.z; v.w += p.w; }
        const float4 bb = *(const float4*)(se_b2 + 4 * t);
        float4 r; r.x = fmaxf(v.x + bb.x, 0.f); r.y = fmaxf(v.y + bb.y, 0.f);
        r.z = fmaxf(v.z + bb.z, 0.f); r.w = fmaxf(v.w + bb.w, 0.f);
        *(float4*)(z_ws + b * ZDIM + 4 * t) = r;
    } else if (t < 128) {
        const int c = t - 64;
        float4 v = part4[256 + c];
        #pragma unroll
        for (int sl = 1; sl < 4; ++sl) { const float4 p = part4[256 + sl * 64 + c];
            v.x += p.x; v.y += p.y; v.z += p.z; v.w += p.w; }
        const float4 bb = *(const float4*)(oe_b2 + 4 * c);
        float4 r; r.x = fmaxf(v.x + bb.x, 0.f); r.y = fmaxf(v.y + bb.y, 0.f);
        r.z = fmaxf(v.z + bb.z, 0.f); r.w = fmaxf(v.w + bb.w, 0.f);
        *(float4*)(z_ws + b * ZDIM + 256 + 4 * c) = r;
    }
}

// ================= fp32 fallback path (ws too small) =================
__global__ void __launch_bounds__(256)
matvec_f32(const float* __restrict__ W, const float* __restrict__ z_ws,
           const float* __restrict__ pred_bias, float* __restrict__ g_ws)
{
    const int b = blockIdx.x >> 5, chunk = blockIdx.x & 31;
    const int wave = threadIdx.x >> 6, lane = threadIdx.x & 63;
    const int row0 = chunk * 64 + wave * 16;
    const float* zb = z_ws + b * ZDIM;
    const float biasv = (lane < 16) ? pred_bias[b * GDIM + row0 + lane] : 0.f;
    const int l4 = lane * 4;
    const float4 z0 = *(const float4*)(zb + l4);
    const float4 z1 = *(const float4*)(zb + 256 + l4);
    const float4 z2 = *(const float4*)(zb + 512 + l4);
    const float4 z3 = *(const float4*)(zb + 768 + l4);
    const float4 z4 = *(const float4*)(zb + 1024 + l4);
    const char* wb = (const char*)W + (size_t)b * GDIM * ZDIM * 4;

    #define ISSUE(p, B) { const char* a_ = wb + (size_t)(row0 + 2 * (p)) * (ZDIM * 4) + lane * 16; \
        _Pragma("unroll") for (int i = 0; i < 10; ++i) B[i] = *(const uint4*)(a_ + i * 1024); }

    uint4 bufa[10], bufb[10];
    ISSUE(0, bufa);
    #pragma unroll
    for (int p = 0; p < 8; ++p) {
        uint4* cur = (p & 1) ? bufb : bufa;
        uint4* nxt = (p & 1) ? bufa : bufb;
        if (p < 7) ISSUE(p + 1, nxt);
        float accA = 0.f, accB = 0.f;
        dot4_(cur[0], z0, accA); dot4_(cur[1], z1, accA); dot4_(cur[2], z2, accA);
        dot4_(cur[3], z3, accA); dot4_(cur[4], z4, accA);
        dot4_(cur[5], z0, accB); dot4_(cur[6], z1, accB); dot4_(cur[7], z2, accB);
        dot4_(cur[8], z3, accB); dot4_(cur[9], z4, accB);
        float s0 = accA + __shfl_xor(accA, 32);
        float s1 = accB + __shfl_xor(accB, 32);
        float u = (lane < 32) ? s0 : s1;
        #pragma unroll
        for (int m = 16; m >= 1; m >>= 1) u += __shfl_xor(u, m);
        const float badd = __shfl(biasv, 2 * p + ((lane >= 32) ? 1 : 0), 64);
        if (lane == 0)       g_ws[b * GDIM + row0 + 2 * p]     = u + badd;
        else if (lane == 32) g_ws[b * GDIM + row0 + 2 * p + 1] = u + badd;
    }
    #undef ISSUE
}

extern "C" void kernel_launch(void* const* d_in, const int* in_sizes, int n_in,
                              void* d_out, int out_size, void* d_ws, size_t ws_size,
                              hipStream_t stream) {
    const float* prv = (const float*)d_in[0];
    const float* pq  = (const float*)d_in[1];
    const float* pro = (const float*)d_in[2];
    const float* pqo = (const float*)d_in[3];
    const float* pc  = (const float*)d_in[4];
    const float* trp = (const float*)d_in[5];
    const float* tq  = (const float*)d_in[6];
    const float* irp = (const float*)d_in[7];
    const float* pw  = (const float*)d_in[8];
    const float* pb  = (const float*)d_in[9];
    const float* se_w1 = (const float*)d_in[10]; const float* se_b1 = (const float*)d_in[11];
    const float* se_w2 = (const float*)d_in[12]; const float* se_b2 = (const float*)d_in[13];
    const float* oe_w1 = (const float*)d_in[14]; const float* oe_b1 = (const float*)d_in[15];
    const float* oe_w2 = (const float*)d_in[16]; const float* oe_b2 = (const float*)d_in[17];
    const float* te_w1 = (const float*)d_in[18]; const float* te_b1 = (const float*)d_in[19];
    const float* te_w2 = (const float*)d_in[20]; const float* te_b2 = (const float*)d_in[21];
    const float* de_w1 = (const float*)d_in[22]; const float* de_b1 = (const float*)d_in[23];
    const float* de_w2 = (const float*)d_in[24]; const float* de_b2 = (const float*)d_in[25];
    const float* de_w3 = (const float*)d_in[26]; const float* de_b3 = (const float*)d_in[27];
    float* outp = (float*)d_out;

    const size_t WB2  = (size_t)BATCH * GDIM * DYNC * 2;   // bf16 dynamic weights
    const size_t AUXB = (size_t)BATCH * (GDIM + ZDIM + GDIM + HDIM + 192) * 4
                      + (size_t)9 * BATCH * 512 * 4        // enc9
                      + (size_t)9 * BATCH * GDIM * 4;      // E
    const bool bf = ws_size >= WB2 + AUXB;

    char* base = (char*)d_ws;
    float* g0_ws; float* z_ws;
    if (bf) {
        g0_ws  = (float*)(base + WB2);
        z_ws   = g0_ws + (size_t)BATCH * GDIM;
    } else {
        g0_ws  = nullptr;
        z_ws   = (float*)base;
    }
    float* g_ws    = z_ws + (size_t)BATCH * ZDIM;
    float* c_ws    = g_ws + (size_t)BATCH * GDIM;
    float* car_ws  = c_ws + (size_t)BATCH * HDIM;
    float* enc9_ws = car_ws + (size_t)BATCH * 192;
    float* E_ws    = enc9_ws + (size_t)9 * BATCH * 512;

    initk<<<dim3(BATCH), dim3(512), 0, stream>>>(prv, pq, pro, pqo, pc, tq, irp,
        se_w1, se_b1, se_w2, se_b2, oe_w1, oe_b1, oe_w2, oe_b2,
        te_w1, te_b1, te_w2, te_b2, z_ws, c_ws, car_ws);

    if (bf) {
        enc_past<<<dim3(BATCH, 9), dim3(512), 0, stream>>>(prv, pq, pro, pqo, pc,
            se_w1, se_b1, se_w2, se_b2, oe_w1, oe_b1, oe_w2, oe_b2, enc9_ws);
        matvec0_conv<<<dim3(BATCH * 32), dim3(256), 0, stream>>>(
            pw, z_ws, pb, (unsigned short*)d_ws, g_ws, g0_ws);
        epass<<<dim3(BATCH * 32), dim3(256), 0, stream>>>(
            (const unsigned short*)d_ws, enc9_ws, g0_ws, E_ws);
        for (int s = 0; s < NSTEPS; ++s) {
            if (s >= 1 && s < NPAST) {
                matvecH<<<dim3(BATCH * 32), dim3(256), 0, stream>>>(
                    (const unsigned short*)d_ws, z_ws,
                    E_ws + (size_t)(s - 1) * BATCH * GDIM, g_ws);
            } else if (s >= NPAST) {
                matvec2_bf16<<<dim3(BATCH * 32), dim3(256), 0, stream>>>(
                    (const unsigned short*)d_ws, z_ws, g0_ws, g_ws);
            }
            const int skip_enc = (s + 1 < NPAST) ? 1 : 0;
            stepk<<<dim3(BATCH), dim3(512), 0, stream>>>(prv, pq, pro, pqo, pc, trp, tq,
                se_w1, se_b1, se_w2, se_b2, oe_w1, oe_b1, oe_w2, oe_b2,
                de_w1, de_b1, de_w2, de_b2, de_w3, de_b3,
                outp, z_ws, g_ws, c_ws, car_ws, s, skip_enc);
        }
    } else {
        for (int s = 0; s < NSTEPS; ++s) {
            matvec_f32<<<dim3(BATCH * 32), dim3(256), 0, stream>>>(pw, z_ws, pb, g_ws);
            stepk<<<dim3(BATCH), dim3(512), 0, stream>>>(prv, pq, pro, pqo, pc, trp, tq,
                se_w1, se_b1, se_w2, se_b2, oe_w1, oe_b1, oe_w2, oe_b2,
                de_w1, de_b1, de_w2, de_b2, de_w3, de_b3,
                outp, z_ws, g_ws, c_ws, car_ws, s, 0);
        }
    }
}

// Round 11
// 4231.864 us; speedup vs baseline: 10.8685x; 1.1778x over previous
//
#include <hip/hip_runtime.h>
#include <hip/hip_bf16.h>
#include <math.h>

#define BATCH 128
#define QD 88
#define HDIM 512
#define ZDIM 1280
#define GDIM 2048
#define PROW 1536          // packed bytes per row: 1024 dyn cols x 12 bit
#define NPAST 10
#define NTRANS 29
#define NSTEPS (NPAST + NTRANS)
#define OUTD 95
#define POSE_ELEMS (BATCH * 30 * 91)

typedef float f32x4 __attribute__((ext_vector_type(4)));

__device__ __forceinline__ float sig_(float x) { return 1.0f / (1.0f + expf(-x)); }
__device__ __forceinline__ void dot4_(const uint4 wv, const float4 zv, float& d) {
    const float4 f = *(const float4*)&wv;
    d = fmaf(f.x, zv.x, d); d = fmaf(f.y, zv.y, d);
    d = fmaf(f.z, zv.z, d); d = fmaf(f.w, zv.w, d);
}
__device__ __forceinline__ void fma4_(float4& acc, float x, const float4 w) {
    acc.x = fmaf(x, w.x, acc.x); acc.y = fmaf(x, w.y, acc.y);
    acc.z = fmaf(x, w.z, acc.z); acc.w = fmaf(x, w.w, acc.w);
}
__device__ __forceinline__ unsigned q12_(float w, float inv) {
    const unsigned u = __float2uint_rn(fmaf(w, inv, 2048.0f));
    return (u > 4095u) ? 4095u : u;
}
// pack 8 values (two uint4 holding fp32 bit patterns) into 3 dwords of 12-bit fields
__device__ __forceinline__ void pack12_(const uint4 a, const uint4 b, float inv,
                                        unsigned& o0, unsigned& o1, unsigned& o2) {
    const unsigned u0 = q12_(__uint_as_float(a.x), inv), u1 = q12_(__uint_as_float(a.y), inv);
    const unsigned u2 = q12_(__uint_as_float(a.z), inv), u3 = q12_(__uint_as_float(a.w), inv);
    const unsigned u4 = q12_(__uint_as_float(b.x), inv), u5 = q12_(__uint_as_float(b.y), inv);
    const unsigned u6 = q12_(__uint_as_float(b.z), inv), u7 = q12_(__uint_as_float(b.w), inv);
    o0 = u0 | (u1 << 12) | (u2 << 24);
    o1 = (u2 >> 8) | (u3 << 4) | (u4 << 16) | (u5 << 28);
    o2 = (u5 >> 4) | (u6 << 8) | (u7 << 20);
}
// signed dot of an 8-weight packet with two float4 z fragments (field - 2048, no bias trick)
__device__ __forceinline__ float dot12_(unsigned d0, unsigned d1, unsigned d2,
                                        const float4 za, const float4 zb) {
    float acc = 0.f;
    acc = fmaf((float)((int)(d0 & 0xFFFu) - 2048), za.x, acc);
    acc = fmaf((float)((int)((d0 >> 12) & 0xFFFu) - 2048), za.y, acc);
    acc = fmaf((float)((int)((d0 >> 24) | ((d1 & 0xFu) << 8)) - 2048), za.z, acc);
    acc = fmaf((float)((int)((d1 >> 4) & 0xFFFu) - 2048), za.w, acc);
    acc = fmaf((float)((int)((d1 >> 16) & 0xFFFu) - 2048), zb.x, acc);
    acc = fmaf((float)((int)((d1 >> 28) | ((d2 & 0xFFu) << 4)) - 2048), zb.y, acc);
    acc = fmaf((float)((int)((d2 >> 8) & 0xFFFu) - 2048), zb.z, acc);
    acc = fmaf((float)((int)(d2 >> 20) - 2048), zb.w, acc);
    return acc;
}
__device__ __forceinline__ float wredmax_(float m) {
    #pragma unroll
    for (int s = 32; s >= 1; s >>= 1) m = fmaxf(m, __shfl_xor(m, s, 64));
    return m;
}
__device__ __forceinline__ float amax4_(const uint4 a, float m) {
    m = fmaxf(m, fabsf(__uint_as_float(a.x))); m = fmaxf(m, fabsf(__uint_as_float(a.y)));
    m = fmaxf(m, fabsf(__uint_as_float(a.z))); m = fmaxf(m, fabsf(__uint_as_float(a.w)));
    return m;
}

// ---- step-0 GEMV over fp32 weights, fused with int12 quantization + static fold ----
// grid 4096 = 128 x 32 chunks; block 256 = 4 waves; wave: 16 rows (8 pairs)
// Packet layout: lane owns cols {4L..4L+3} and {256+4L..256+4L+3} of each 512-col half.
__global__ void __launch_bounds__(256)
matvec0_conv(const float* __restrict__ W, const float* __restrict__ z_ws,
             const float* __restrict__ pred_bias, unsigned char* __restrict__ Wp,
             float* __restrict__ scale_ws, float* __restrict__ g_ws, float* __restrict__ g0_ws)
{
    const int b = blockIdx.x >> 5, chunk = blockIdx.x & 31;
    const int wave = threadIdx.x >> 6, lane = threadIdx.x & 63;
    const int row0 = chunk * 64 + wave * 16;
    const float* zb = z_ws + b * ZDIM;
    const float biasv = (lane < 16) ? pred_bias[b * GDIM + row0 + lane] : 0.f;
    const int l4 = lane * 4;
    const float4 z0 = *(const float4*)(zb + l4);
    const float4 z1 = *(const float4*)(zb + 256 + l4);
    const float4 zh = *(const float4*)(zb + 512 + l4);
    const float4 z3 = *(const float4*)(zb + 768 + l4);
    const float4 z4 = *(const float4*)(zb + 1024 + l4);
    const char* wb = (const char*)W + (size_t)b * GDIM * ZDIM * 4;
    char* dstB = (char*)Wp + (size_t)b * GDIM * PROW;

    #define ISSUE(p, B) { const char* a_ = wb + (size_t)(row0 + 2 * (p)) * (ZDIM * 4) + lane * 16; \
        _Pragma("unroll") for (int i = 0; i < 10; ++i) B[i] = *(const uint4*)(a_ + i * 1024); }

    uint4 bufa[10], bufb[10];
    ISSUE(0, bufa);
    #pragma unroll
    for (int p = 0; p < 8; ++p) {
        uint4* cur = (p & 1) ? bufb : bufa;
        uint4* nxt = (p & 1) ? bufa : bufb;
        if (p < 7) ISSUE(p + 1, nxt);
        float dynA = 0.f, dynB = 0.f, statA = 0.f, statB = 0.f;
        dot4_(cur[0], z0, dynA); dot4_(cur[1], z1, dynA);
        dot4_(cur[2], zh, statA);
        dot4_(cur[3], z3, dynA); dot4_(cur[4], z4, dynA);
        dot4_(cur[5], z0, dynB); dot4_(cur[6], z1, dynB);
        dot4_(cur[7], zh, statB);
        dot4_(cur[8], z3, dynB); dot4_(cur[9], z4, dynB);
        // per-row max over dynamic cols, wave-wide
        float m0 = 0.f, m1 = 0.f;
        m0 = amax4_(cur[0], m0); m0 = amax4_(cur[1], m0);
        m0 = amax4_(cur[3], m0); m0 = amax4_(cur[4], m0);
        m1 = amax4_(cur[5], m1); m1 = amax4_(cur[6], m1);
        m1 = amax4_(cur[8], m1); m1 = amax4_(cur[9], m1);
        m0 = wredmax_(m0); m1 = wredmax_(m1);
        const float s0 = m0 * (1.f / 2047.f), s1 = m1 * (1.f / 2047.f);
        const float inv0 = (m0 > 0.f) ? 2047.f / m0 : 0.f;
        const float inv1 = (m1 > 0.f) ? 2047.f / m1 : 0.f;
        // pack + store: row r state at +0, h at +768; row r+1 at +1536/+2304
        {
            char* rp = dstB + (size_t)(row0 + 2 * p) * PROW + lane * 12;
            unsigned o0, o1, o2;
            pack12_(cur[0], cur[1], inv0, o0, o1, o2);
            __builtin_nontemporal_store(o0, (unsigned*)(rp));
            __builtin_nontemporal_store(o1, (unsigned*)(rp + 4));
            __builtin_nontemporal_store(o2, (unsigned*)(rp + 8));
            pack12_(cur[3], cur[4], inv0, o0, o1, o2);
            __builtin_nontemporal_store(o0, (unsigned*)(rp + 768));
            __builtin_nontemporal_store(o1, (unsigned*)(rp + 772));
            __builtin_nontemporal_store(o2, (unsigned*)(rp + 776));
            pack12_(cur[5], cur[6], inv1, o0, o1, o2);
            __builtin_nontemporal_store(o0, (unsigned*)(rp + 1536));
            __builtin_nontemporal_store(o1, (unsigned*)(rp + 1540));
            __builtin_nontemporal_store(o2, (unsigned*)(rp + 1544));
            pack12_(cur[8], cur[9], inv1, o0, o1, o2);
            __builtin_nontemporal_store(o0, (unsigned*)(rp + 2304));
            __builtin_nontemporal_store(o1, (unsigned*)(rp + 2308));
            __builtin_nontemporal_store(o2, (unsigned*)(rp + 2312));
        }
        if (lane == 0) { scale_ws[b * GDIM + row0 + 2 * p] = s0;
                         scale_ws[b * GDIM + row0 + 2 * p + 1] = s1; }
        float sd0 = dynA + __shfl_xor(dynA, 32);
        float sd1 = dynB + __shfl_xor(dynB, 32);
        float ud = (lane < 32) ? sd0 : sd1;
        float ss0 = statA + __shfl_xor(statA, 32);
        float ss1 = statB + __shfl_xor(statB, 32);
        float us = (lane < 32) ? ss0 : ss1;
        #pragma unroll
        for (int m = 16; m >= 1; m >>= 1) { ud += __shfl_xor(ud, m); us += __shfl_xor(us, m); }
        const float badd = __shfl(biasv, 2 * p + ((lane >= 32) ? 1 : 0), 64);
        if (lane == 0 || lane == 32) {
            const int r = row0 + 2 * p + ((lane >= 32) ? 1 : 0);
            g0_ws[b * GDIM + r] = us + badd;
            g_ws[b * GDIM + r]  = ud + us + badd;
        }
    }
    #undef ISSUE
}

// ---- E-pass: E[s][b][row] = g0 + s_row * (W_state . enc[s])   (state half only) ----
// FRAGMENTS MATCH PACKET LAYOUT: lane dots enc cols {4L..4L+3} and {256+4L..256+4L+3}.
__global__ void __launch_bounds__(256)
epass(const unsigned char* __restrict__ Wp, const float* __restrict__ enc9,
      const float* __restrict__ scale_ws, const float* __restrict__ g0_ws,
      float* __restrict__ E_ws)
{
    const int b = blockIdx.x >> 5, chunk = blockIdx.x & 31;
    const int wave = threadIdx.x >> 6, lane = threadIdx.x & 63;
    const int row0 = chunk * 64 + wave * 16;
    const int l4 = lane * 4;
    float4 eA[9], eB[9];
    #pragma unroll
    for (int s = 0; s < 9; ++s) {
        const float* eb = enc9 + ((size_t)s * BATCH + b) * 512;
        eA[s] = *(const float4*)(eb + l4);
        eB[s] = *(const float4*)(eb + 256 + l4);
    }
    const float g0v = (lane < 16) ? g0_ws[b * GDIM + row0 + lane] : 0.f;
    const float scv = (lane < 16) ? scale_ws[b * GDIM + row0 + lane] : 0.f;
    const char* wb = (const char*)Wp + (size_t)b * GDIM * PROW;

    #define ISSUE(p, B) { const char* a_ = wb + (size_t)(row0 + 2 * (p)) * PROW + lane * 12; \
        B[0] = __builtin_nontemporal_load((const unsigned*)(a_)); \
        B[1] = __builtin_nontemporal_load((const unsigned*)(a_ + 4)); \
        B[2] = __builtin_nontemporal_load((const unsigned*)(a_ + 8)); \
        B[3] = __builtin_nontemporal_load((const unsigned*)(a_ + 1536)); \
        B[4] = __builtin_nontemporal_load((const unsigned*)(a_ + 1540)); \
        B[5] = __builtin_nontemporal_load((const unsigned*)(a_ + 1544)); }

    unsigned bufa[6], bufb[6];
    ISSUE(0, bufa);
    #pragma unroll
    for (int p = 0; p < 8; ++p) {
        unsigned* cur = (p & 1) ? bufb : bufa;
        unsigned* nxt = (p & 1) ? bufa : bufb;
        if (p < 7) ISSUE(p + 1, nxt);
        const float badd = __shfl(g0v, 2 * p + ((lane >= 32) ? 1 : 0), 64);
        const float srow = __shfl(scv, 2 * p + ((lane >= 32) ? 1 : 0), 64);
        #pragma unroll
        for (int s = 0; s < 9; ++s) {
            const float aA = dot12_(cur[0], cur[1], cur[2], eA[s], eB[s]);
            const float aB = dot12_(cur[3], cur[4], cur[5], eA[s], eB[s]);
            const float s0 = aA + __shfl_xor(aA, 32);
            const float s1 = aB + __shfl_xor(aB, 32);
            float u = (lane < 32) ? s0 : s1;
            #pragma unroll
            for (int m = 16; m >= 1; m >>= 1) u += __shfl_xor(u, m);
            const float val = badd + srow * u;
            if (lane == 0)
                E_ws[((size_t)s * BATCH + b) * GDIM + row0 + 2 * p] = val;
            else if (lane == 32)
                E_ws[((size_t)s * BATCH + b) * GDIM + row0 + 2 * p + 1] = val;
        }
    }
    #undef ISSUE
}

// ---- past-step GEMV (s=1..9): gates = E[s] + s_row*(W_h . h)  (h half, L3-resident) ----
__global__ void __launch_bounds__(256)
matvecH(const unsigned char* __restrict__ Wp, const float* __restrict__ z_ws,
        const float* __restrict__ scale_ws, const float* __restrict__ Es,
        float* __restrict__ g_ws)
{
    const int b = blockIdx.x >> 5, chunk = blockIdx.x & 31;
    const int wave = threadIdx.x >> 6, lane = threadIdx.x & 63;
    const int row0 = chunk * 64 + wave * 16;
    const float* zb = z_ws + b * ZDIM;
    const int l4 = lane * 4;
    const float4 z3 = *(const float4*)(zb + 768 + l4);
    const float4 z4 = *(const float4*)(zb + 1024 + l4);
    const float Ev  = (lane < 16) ? Es[b * GDIM + row0 + lane] : 0.f;
    const float scv = (lane < 16) ? scale_ws[b * GDIM + row0 + lane] : 0.f;
    const char* wb = (const char*)Wp + (size_t)b * GDIM * PROW;

    #define ISSUE(p, B) { const char* a_ = wb + (size_t)(row0 + 2 * (p)) * PROW + 768 + lane * 12; \
        B[0] = *(const unsigned*)(a_);        B[1] = *(const unsigned*)(a_ + 4); \
        B[2] = *(const unsigned*)(a_ + 8); \
        B[3] = *(const unsigned*)(a_ + 1536); B[4] = *(const unsigned*)(a_ + 1540); \
        B[5] = *(const unsigned*)(a_ + 1544); }

    unsigned buf0[6], buf1[6], buf2[6];
    ISSUE(0, buf0);
    ISSUE(1, buf1);
    #pragma unroll
    for (int p = 0; p < 8; ++p) {
        unsigned* cur = (p % 3 == 0) ? buf0 : (p % 3 == 1) ? buf1 : buf2;
        unsigned* nxt = ((p + 2) % 3 == 0) ? buf0 : ((p + 2) % 3 == 1) ? buf1 : buf2;
        if (p < 6) ISSUE(p + 2, nxt);
        const float aA = dot12_(cur[0], cur[1], cur[2], z3, z4);
        const float aB = dot12_(cur[3], cur[4], cur[5], z3, z4);
        const float s0 = aA + __shfl_xor(aA, 32);
        const float s1 = aB + __shfl_xor(aB, 32);
        float u = (lane < 32) ? s0 : s1;
        #pragma unroll
        for (int m = 16; m >= 1; m >>= 1) u += __shfl_xor(u, m);
        const float badd = __shfl(Ev, 2 * p + ((lane >= 32) ? 1 : 0), 64);
        const float srow = __shfl(scv, 2 * p + ((lane >= 32) ? 1 : 0), 64);
        const float val = badd + srow * u;
        if (lane == 0)       g_ws[b * GDIM + row0 + 2 * p]     = val;
        else if (lane == 32) g_ws[b * GDIM + row0 + 2 * p + 1] = val;
    }
    #undef ISSUE
}

// ---- transition-step GEMV over int12 weights (full 1024 dyn cols) ----
__global__ void __launch_bounds__(256)
matvec12(const unsigned char* __restrict__ Wp, const float* __restrict__ z_ws,
         const float* __restrict__ scale_ws, const float* __restrict__ g0_ws,
         float* __restrict__ g_ws)
{
    const int b = blockIdx.x >> 5, chunk = blockIdx.x & 31;
    const int wave = threadIdx.x >> 6, lane = threadIdx.x & 63;
    const int row0 = chunk * 64 + wave * 16;
    const float* zb = z_ws + b * ZDIM;
    const int l4 = lane * 4;
    const float4 z0 = *(const float4*)(zb + l4);
    const float4 z1 = *(const float4*)(zb + 256 + l4);
    const float4 z3 = *(const float4*)(zb + 768 + l4);
    const float4 z4 = *(const float4*)(zb + 1024 + l4);
    const float g0v = (lane < 16) ? g0_ws[b * GDIM + row0 + lane] : 0.f;
    const float scv = (lane < 16) ? scale_ws[b * GDIM + row0 + lane] : 0.f;
    const char* wb = (const char*)Wp + (size_t)b * GDIM * PROW;

    #define ISSUE(p, B) { const char* a_ = wb + (size_t)(row0 + 2 * (p)) * PROW + lane * 12; \
        B[0] = __builtin_nontemporal_load((const unsigned*)(a_)); \
        B[1] = __builtin_nontemporal_load((const unsigned*)(a_ + 4)); \
        B[2] = __builtin_nontemporal_load((const unsigned*)(a_ + 8)); \
        B[3] = __builtin_nontemporal_load((const unsigned*)(a_ + 768)); \
        B[4] = __builtin_nontemporal_load((const unsigned*)(a_ + 772)); \
        B[5] = __builtin_nontemporal_load((const unsigned*)(a_ + 776)); \
        B[6] = __builtin_nontemporal_load((const unsigned*)(a_ + 1536)); \
        B[7] = __builtin_nontemporal_load((const unsigned*)(a_ + 1540)); \
        B[8] = __builtin_nontemporal_load((const unsigned*)(a_ + 1544)); \
        B[9] = __builtin_nontemporal_load((const unsigned*)(a_ + 2304)); \
        B[10] = __builtin_nontemporal_load((const unsigned*)(a_ + 2308)); \
        B[11] = __builtin_nontemporal_load((const unsigned*)(a_ + 2312)); }

    unsigned buf0[12], buf1[12], buf2[12];
    ISSUE(0, buf0);
    ISSUE(1, buf1);
    #pragma unroll
    for (int p = 0; p < 8; ++p) {
        unsigned* cur = (p % 3 == 0) ? buf0 : (p % 3 == 1) ? buf1 : buf2;
        unsigned* nxt = ((p + 2) % 3 == 0) ? buf0 : ((p + 2) % 3 == 1) ? buf1 : buf2;
        if (p < 6) ISSUE(p + 2, nxt);
        const float aA = dot12_(cur[0], cur[1], cur[2], z0, z1)
                       + dot12_(cur[3], cur[4], cur[5], z3, z4);
        const float aB = dot12_(cur[6], cur[7], cur[8], z0, z1)
                       + dot12_(cur[9], cur[10], cur[11], z3, z4);
        const float s0 = aA + __shfl_xor(aA, 32);
        const float s1 = aB + __shfl_xor(aB, 32);
        float u = (lane < 32) ? s0 : s1;
        #pragma unroll
        for (int m = 16; m >= 1; m >>= 1) u += __shfl_xor(u, m);
        const float badd = __shfl(g0v, 2 * p + ((lane >= 32) ? 1 : 0), 64);
        const float srow = __shfl(scv, 2 * p + ((lane >= 32) ? 1 : 0), 64);
        const float val = badd + srow * u;
        if (lane == 0)       g_ws[b * GDIM + row0 + 2 * p]     = val;
        else if (lane == 32) g_ws[b * GDIM + row0 + 2 * p + 1] = val;
    }
    #undef ISSUE
}

// ---------------- init: state=0, h_target, step-0 encoders ----------------
__global__ void __launch_bounds__(512)
initk(const float* __restrict__ past_root_vel, const float* __restrict__ past_quats,
      const float* __restrict__ past_root_offset, const float* __restrict__ past_quat_offset,
      const float* __restrict__ past_contacts, const float* __restrict__ target_quats,
      const float* __restrict__ init_root_pos,
      const float* __restrict__ se_w1, const float* __restrict__ se_b1,
      const float* __restrict__ se_w2, const float* __restrict__ se_b2,
      const float* __restrict__ oe_w1, const float* __restrict__ oe_b1,
      const float* __restrict__ oe_w2, const float* __restrict__ oe_b2,
      const float* __restrict__ te_w1, const float* __restrict__ te_b1,
      const float* __restrict__ te_w2, const float* __restrict__ te_b2,
      float* __restrict__ z_ws, float* __restrict__ c_ws, float* __restrict__ car_ws)
{
    const int b = blockIdx.x, t = threadIdx.x;
    __shared__ float tq[QD], bufA[512], bufB[512], sv[95], ov[91];

    if (t < 192) car_ws[b * 192 + t] = (t < 3) ? init_root_pos[b * 3 + t] : 0.f;
    c_ws[b * HDIM + t] = 0.f;
    z_ws[b * ZDIM + 768 + t] = 0.f;
    if (t < QD) tq[t] = target_quats[b * QD + t];
    if (t < 4)  sv[t] = past_contacts[b * NPAST * 4 + t];
    if (t < QD) { sv[4 + t] = past_quats[b * NPAST * QD + t];
                  ov[3 + t] = past_quat_offset[b * NPAST * QD + t]; }
    if (t < 3)  { sv[92 + t] = past_root_vel[b * NPAST * 3 + t];
                  ov[t]      = past_root_offset[b * NPAST * 3 + t]; }
    __syncthreads();
    {
        float a = te_b1[t];
        #pragma unroll 8
        for (int i = 0; i < QD; ++i) a = fmaf(tq[i], te_w1[i * 512 + t], a);
        bufA[t] = fmaxf(a, 0.f);
    }
    __syncthreads();
    if (t < 256) {
        float a = te_b2[t];
        #pragma unroll 8
        for (int i = 0; i < 512; ++i) a = fmaf(bufA[i], te_w2[i * 256 + t], a);
        z_ws[b * ZDIM + 512 + t] = fmaxf(a, 0.f);
    }
    __syncthreads();
    {
        float aS = se_b1[t], aO = oe_b1[t];
        #pragma unroll 8
        for (int i = 0; i < 91; ++i) { aS = fmaf(sv[i], se_w1[i * 512 + t], aS);
                                       aO = fmaf(ov[i], oe_w1[i * 512 + t], aO); }
        #pragma unroll
        for (int i = 91; i < 95; ++i) aS = fmaf(sv[i], se_w1[i * 512 + t], aS);
        bufA[t] = fmaxf(aS, 0.f);
        bufB[t] = fmaxf(aO, 0.f);
    }
    __syncthreads();
    if (t < 256) {
        float a = se_b2[t];
        #pragma unroll 8
        for (int i = 0; i < 512; ++i) a = fmaf(bufA[i], se_w2[i * 256 + t], a);
        z_ws[b * ZDIM + t] = fmaxf(a, 0.f);
    } else {
        const int j = t - 256;
        float a = oe_b2[j];
        #pragma unroll 8
        for (int i = 0; i < 512; ++i) a = fmaf(bufB[i], oe_w2[i * 256 + j], a);
        z_ws[b * ZDIM + 256 + j] = fmaxf(a, 0.f);
    }
}

// ---- batch-encode past steps 1..9 -> enc9[(s-1)*BATCH + b][512] ----
__global__ void __launch_bounds__(512)
enc_past(const float* __restrict__ past_root_vel, const float* __restrict__ past_quats,
         const float* __restrict__ past_root_offset, const float* __restrict__ past_quat_offset,
         const float* __restrict__ past_contacts,
         const float* __restrict__ se_w1, const float* __restrict__ se_b1,
         const float* __restrict__ se_w2, const float* __restrict__ se_b2,
         const float* __restrict__ oe_w1, const float* __restrict__ oe_b1,
         const float* __restrict__ oe_w2, const float* __restrict__ oe_b2,
         float* __restrict__ enc9)
{
    const int b = blockIdx.x, t = threadIdx.x;
    const int s = blockIdx.y + 1;
    __shared__ float bufA[512], bufB[512], sv[95], ov[91];

    if (t < 4)  sv[t] = past_contacts[(b * NPAST + s) * 4 + t];
    if (t < QD) { sv[4 + t] = past_quats[(b * NPAST + s) * QD + t];
                  ov[3 + t] = past_quat_offset[(b * NPAST + s) * QD + t]; }
    if (t < 3)  { sv[92 + t] = past_root_vel[(b * NPAST + s) * 3 + t];
                  ov[t]      = past_root_offset[(b * NPAST + s) * 3 + t]; }
    __syncthreads();
    {
        float aS = se_b1[t], aO = oe_b1[t];
        #pragma unroll 8
        for (int i = 0; i < 91; ++i) { aS = fmaf(sv[i], se_w1[i * 512 + t], aS);
                                       aO = fmaf(ov[i], oe_w1[i * 512 + t], aO); }
        #pragma unroll
        for (int i = 91; i < 95; ++i) aS = fmaf(sv[i], se_w1[i * 512 + t], aS);
        bufA[t] = fmaxf(aS, 0.f);
        bufB[t] = fmaxf(aO, 0.f);
    }
    __syncthreads();
    float* dst = enc9 + ((size_t)(s - 1) * BATCH + b) * 512;
    if (t < 256) {
        float a = se_b2[t];
        #pragma unroll 8
        for (int i = 0; i < 512; ++i) a = fmaf(bufA[i], se_w2[i * 256 + t], a);
        dst[t] = fmaxf(a, 0.f);
    } else {
        const int j = t - 256;
        float a = oe_b2[j];
        #pragma unroll 8
        for (int i = 0; i < 512; ++i) a = fmaf(bufB[i], oe_w2[i * 256 + j], a);
        dst[256 + j] = fmaxf(a, 0.f);
    }
}

// ---------------- per-step: LSTM + decoder + state update + next encoders ----------------
__global__ void __launch_bounds__(512)
stepk(const float* __restrict__ past_root_vel, const float* __restrict__ past_quats,
      const float* __restrict__ past_root_offset, const float* __restrict__ past_quat_offset,
      const float* __restrict__ past_contacts, const float* __restrict__ target_root_pos,
      const float* __restrict__ target_quats,
      const float* __restrict__ se_w1, const float* __restrict__ se_b1,
      const float* __restrict__ se_w2, const float* __restrict__ se_b2,
      const float* __restrict__ oe_w1, const float* __restrict__ oe_b1,
      const float* __restrict__ oe_w2, const float* __restrict__ oe_b2,
      const float* __restrict__ de_w1, const float* __restrict__ de_b1,
      const float* __restrict__ de_w2, const float* __restrict__ de_b2,
      const float* __restrict__ de_w3, const float* __restrict__ de_b3,
      float* __restrict__ out, float* __restrict__ z_ws, const float* __restrict__ g_ws,
      float* __restrict__ c_ws, float* __restrict__ car_ws, int s, int skip_enc)
{
    const int b = blockIdx.x, t = threadIdx.x;
    __shared__ float4 part4[512];
    __shared__ __align__(16) float h2s[HDIM], bufA[512], bufB[512], d2[256];
    __shared__ float outv[OUTD], nq[QD], sv[95], ov[91], carryL[192], tq[QD], trp[3];
    __shared__ float rvn[3], globn[3], contn[4];

    if (t < 192) carryL[t] = car_ws[b * 192 + t];
    if (t < QD) tq[t] = target_quats[b * QD + t];
    if (t < 3)  trp[t] = target_root_pos[b * 3 + t];

    {
        const float* g = g_ws + b * GDIM;
        const float ig = g[t], fg = g[512 + t], gg = g[1024 + t], og = g[1536 + t];
        const float c2 = sig_(fg) * c_ws[b * HDIM + t] + sig_(ig) * tanhf(gg);
        c_ws[b * HDIM + t] = c2;
        const float h2 = sig_(og) * tanhf(c2);
        h2s[t] = h2;
        z_ws[b * ZDIM + 768 + t] = h2;
    }
    __syncthreads();
    {
        const int c = t & 127, s4 = t >> 7;
        float4 acc = {0.f, 0.f, 0.f, 0.f};
        const float* w = de_w1 + (size_t)(s4 * 128) * 512 + 4 * c;
        #pragma unroll 8
        for (int k = 0; k < 128; ++k)
            fma4_(acc, h2s[s4 * 128 + k], *(const float4*)(w + (size_t)k * 512));
        part4[t] = acc;
    }
    __syncthreads();
    if (t < 128) {
        float4 v = part4[t];
        #pragma unroll
        for (int s4 = 1; s4 < 4; ++s4) { const float4 p = part4[s4 * 128 + t];
            v.x += p.x; v.y += p.y; v.z += p.z; v.w += p.w; }
        const float4 bb = *(const float4*)(de_b1 + 4 * t);
        float4 r; r.x = fmaxf(v.x + bb.x, 0.f); r.y = fmaxf(v.y + bb.y, 0.f);
        r.z = fmaxf(v.z + bb.z, 0.f); r.w = fmaxf(v.w + bb.w, 0.f);
        *(float4*)&bufA[4 * t] = r;
    }
    __syncthreads();
    {
        const int c = t & 63, s8 = t >> 6;
        float4 acc = {0.f, 0.f, 0.f, 0.f};
        const float* w = de_w2 + (size_t)(s8 * 64) * 256 + 4 * c;
        #pragma unroll 8
        for (int k = 0; k < 64; ++k)
            fma4_(acc, bufA[s8 * 64 + k], *(const float4*)(w + (size_t)k * 256));
        part4[t] = acc;
    }
    __syncthreads();
    if (t < 64) {
        float4 v = part4[t];
        #pragma unroll
        for (int s8 = 1; s8 < 8; ++s8) { const float4 p = part4[s8 * 64 + t];
            v.x += p.x; v.y += p.y; v.z += p.z; v.w += p.w; }
        const float4 bb = *(const float4*)(de_b2 + 4 * t);
        float4 r; r.x = fmaxf(v.x + bb.x, 0.f); r.y = fmaxf(v.y + bb.y, 0.f);
        r.z = fmaxf(v.z + bb.z, 0.f); r.w = fmaxf(v.w + bb.w, 0.f);
        *(float4*)&d2[4 * t] = r;
    }
    __syncthreads();
    if (t < OUTD) {
        float acc = de_b3[t];
        #pragma unroll 16
        for (int i = 0; i < 256; ++i) acc = fmaf(d2[i], de_w3[i * OUTD + t], acc);
        outv[t] = acc;
    }
    __syncthreads();

    const bool pastS = (s < NPAST);
    if (t < QD) {
        const float qin = pastS ? past_quats[(b * NPAST + s) * QD + t] : carryL[10 + t];
        nq[t] = outv[t] + qin;
    }
    __syncthreads();
    if (t < 22) {
        const float a = nq[4 * t], b2 = nq[4 * t + 1], c3 = nq[4 * t + 2], d4 = nq[4 * t + 3];
        const float inv = 1.f / fmaxf(sqrtf(a * a + b2 * b2 + c3 * c3 + d4 * d4), 1e-12f);
        nq[4 * t] = a * inv; nq[4 * t + 1] = b2 * inv; nq[4 * t + 2] = c3 * inv; nq[4 * t + 3] = d4 * inv;
    }
    if (t < 3) {
        const float rin = pastS ? past_root_vel[(b * NPAST + s) * 3 + t] : carryL[3 + t];
        const float nrv = outv[88 + t] + rin;
        const float g = carryL[t] + (pastS ? rin : nrv);
        rvn[t] = nrv; globn[t] = g;
    }
    if (t < 4) contn[t] = sig_(outv[91 + t]);
    __syncthreads();

    if (t < 3) { car_ws[b * 192 + t] = globn[t]; car_ws[b * 192 + 3 + t] = rvn[t];
                 car_ws[b * 192 + 186 + t] = globn[t] - trp[t]; }
    if (t < 4) car_ws[b * 192 + 6 + t] = contn[t];
    if (t < QD) { car_ws[b * 192 + 10 + t] = nq[t]; car_ws[b * 192 + 98 + t] = nq[t] - tq[t]; }
    if (s == NPAST - 1) {
        const size_t pb = (size_t)b * 30 * 91;
        if (t < 3)  out[pb + t] = rvn[t];
        if (t < QD) out[pb + 3 + t] = nq[t];
        if (t < 4)  out[POSE_ELEMS + (size_t)b * 30 * 4 + t] = contn[t];
    } else if (!pastS) {
        const int k = s - NPAST + 1;
        const size_t pb = ((size_t)b * 30 + k) * 91;
        if (t < 3)  out[pb + t] = globn[t];
        if (t < QD) out[pb + 3 + t] = nq[t];
        if (t < 4)  out[POSE_ELEMS + ((size_t)b * 30 + k) * 4 + t] = contn[t];
    }
    if (s == NSTEPS - 1) return;
    if (skip_enc) return;

    const int nx = s + 1;
    if (nx < NPAST) {
        if (t < 4)  sv[t] = past_contacts[(b * NPAST + nx) * 4 + t];
        if (t < QD) { sv[4 + t] = past_quats[(b * NPAST + nx) * QD + t];
                      ov[3 + t] = past_quat_offset[(b * NPAST + nx) * QD + t]; }
        if (t < 3)  { sv[92 + t] = past_root_vel[(b * NPAST + nx) * 3 + t];
                      ov[t]      = past_root_offset[(b * NPAST + nx) * 3 + t]; }
    } else {
        if (t < 4)  sv[t] = contn[t];
        if (t < QD) { sv[4 + t] = nq[t]; ov[3 + t] = nq[t] - tq[t]; }
        if (t < 3)  { sv[92 + t] = rvn[t]; ov[t] = globn[t] - trp[t]; }
    }
    __syncthreads();
    {
        const int tt = t & 255, enc = t >> 8;
        const int c = tt & 127, sl = tt >> 7;
        const float* inp = enc ? ov : sv;
        const float* w1  = enc ? oe_w1 : se_w1;
        const int nin  = enc ? 91 : 95;
        const int half = enc ? 46 : 48;
        const int i0 = sl * half;
        const int iend = (i0 + half < nin) ? (i0 + half) : nin;
        float4 acc = {0.f, 0.f, 0.f, 0.f};
        #pragma unroll 8
        for (int k = 0; k < 48; ++k) {
            const int i = i0 + k;
            if (i < iend) fma4_(acc, inp[i], *(const float4*)(w1 + (size_t)i * 512 + 4 * c));
        }
        part4[enc * 256 + tt] = acc;
    }
    __syncthreads();
    if (t < 128) {
        const float4 a = part4[t], b2 = part4[128 + t];
        const float4 bb = *(const float4*)(se_b1 + 4 * t);
        float4 r; r.x = fmaxf(a.x + b2.x + bb.x, 0.f); r.y = fmaxf(a.y + b2.y + bb.y, 0.f);
        r.z = fmaxf(a.z + b2.z + bb.z, 0.f); r.w = fmaxf(a.w + b2.w + bb.w, 0.f);
        *(float4*)&bufA[4 * t] = r;
    } else if (t < 256) {
        const int c = t - 128;
        const float4 a = part4[256 + c], b2 = part4[384 + c];
        const float4 bb = *(const float4*)(oe_b1 + 4 * c);
        float4 r; r.x = fmaxf(a.x + b2.x + bb.x, 0.f); r.y = fmaxf(a.y + b2.y + bb.y, 0.f);
        r.z = fmaxf(a.z + b2.z + bb.z, 0.f); r.w = fmaxf(a.w + b2.w + bb.w, 0.f);
        *(float4*)&bufB[4 * c] = r;
    }
    __syncthreads();
    {
        const int tt = t & 255, enc = t >> 8;
        const int c = tt & 63, sl = tt >> 6;
        const float* inp = enc ? bufB : bufA;
        const float* w2  = enc ? oe_w2 : se_w2;
        float4 acc = {0.f, 0.f, 0.f, 0.f};
        const float* w = w2 + (size_t)(sl * 128) * 256 + 4 * c;
        #pragma unroll 8
        for (int k = 0; k < 128; ++k)
            fma4_(acc, inp[sl * 128 + k], *(const float4*)(w + (size_t)k * 256));
        part4[enc * 256 + tt] = acc;
    }
    __syncthreads();
    if (t < 64) {
        float4 v = part4[t];
        #pragma unroll
        for (int sl = 1; sl < 4; ++sl) { const float4 p = part4[sl * 64 + t];
            v.x += p.x; v.y += p.y; v.z += p.z; v.w += p.w; }
        const float4 bb = *(const float4*)(se_b2 + 4 * t);
        float4 r; r.x = fmaxf(v.x + bb.x, 0.f); r.y = fmaxf(v.y + bb.y, 0.f);
        r.z = fmaxf(v.z + bb.z, 0.f); r.w = fmaxf(v.w + bb.w, 0.f);
        *(float4*)(z_ws + b * ZDIM + 4 * t) = r;
    } else if (t < 128) {
        const int c = t - 64;
        float4 v = part4[256 + c];
        #pragma unroll
        for (int sl = 1; sl < 4; ++sl) { const float4 p = part4[256 + sl * 64 + c];
            v.x += p.x; v.y += p.y; v.z += p.z; v.w += p.w; }
        const float4 bb = *(const float4*)(oe_b2 + 4 * c);
        float4 r; r.x = fmaxf(v.x + bb.x, 0.f); r.y = fmaxf(v.y + bb.y, 0.f);
        r.z = fmaxf(v.z + bb.z, 0.f); r.w = fmaxf(v.w + bb.w, 0.f);
        *(float4*)(z_ws + b * ZDIM + 256 + 4 * c) = r;
    }
}

// ================= fp32 fallback path (ws too small) =================
__global__ void __launch_bounds__(256)
matvec_f32(const float* __restrict__ W, const float* __restrict__ z_ws,
           const float* __restrict__ pred_bias, float* __restrict__ g_ws)
{
    const int b = blockIdx.x >> 5, chunk = blockIdx.x & 31;
    const int wave = threadIdx.x >> 6, lane = threadIdx.x & 63;
    const int row0 = chunk * 64 + wave * 16;
    const float* zb = z_ws + b * ZDIM;
    const float biasv = (lane < 16) ? pred_bias[b * GDIM + row0 + lane] : 0.f;
    const int l4 = lane * 4;
    const float4 z0 = *(const float4*)(zb + l4);
    const float4 z1 = *(const float4*)(zb + 256 + l4);
    const float4 z2 = *(const float4*)(zb + 512 + l4);
    const float4 z3 = *(const float4*)(zb + 768 + l4);
    const float4 z4 = *(const float4*)(zb + 1024 + l4);
    const char* wb = (const char*)W + (size_t)b * GDIM * ZDIM * 4;

    #define ISSUE(p, B) { const char* a_ = wb + (size_t)(row0 + 2 * (p)) * (ZDIM * 4) + lane * 16; \
        _Pragma("unroll") for (int i = 0; i < 10; ++i) B[i] = *(const uint4*)(a_ + i * 1024); }

    uint4 bufa[10], bufb[10];
    ISSUE(0, bufa);
    #pragma unroll
    for (int p = 0; p < 8; ++p) {
        uint4* cur = (p & 1) ? bufb : bufa;
        uint4* nxt = (p & 1) ? bufa : bufb;
        if (p < 7) ISSUE(p + 1, nxt);
        float accA = 0.f, accB = 0.f;
        dot4_(cur[0], z0, accA); dot4_(cur[1], z1, accA); dot4_(cur[2], z2, accA);
        dot4_(cur[3], z3, accA); dot4_(cur[4], z4, accA);
        dot4_(cur[5], z0, accB); dot4_(cur[6], z1, accB); dot4_(cur[7], z2, accB);
        dot4_(cur[8], z3, accB); dot4_(cur[9], z4, accB);
        float s0 = accA + __shfl_xor(accA, 32);
        float s1 = accB + __shfl_xor(accB, 32);
        float u = (lane < 32) ? s0 : s1;
        #pragma unroll
        for (int m = 16; m >= 1; m >>= 1) u += __shfl_xor(u, m);
        const float badd = __shfl(biasv, 2 * p + ((lane >= 32) ? 1 : 0), 64);
        if (lane == 0)       g_ws[b * GDIM + row0 + 2 * p]     = u + badd;
        else if (lane == 32) g_ws[b * GDIM + row0 + 2 * p + 1] = u + badd;
    }
    #undef ISSUE
}

extern "C" void kernel_launch(void* const* d_in, const int* in_sizes, int n_in,
                              void* d_out, int out_size, void* d_ws, size_t ws_size,
                              hipStream_t stream) {
    const float* prv = (const float*)d_in[0];
    const float* pq  = (const float*)d_in[1];
    const float* pro = (const float*)d_in[2];
    const float* pqo = (const float*)d_in[3];
    const float* pc  = (const float*)d_in[4];
    const float* trp = (const float*)d_in[5];
    const float* tq  = (const float*)d_in[6];
    const float* irp = (const float*)d_in[7];
    const float* pw  = (const float*)d_in[8];
    const float* pb  = (const float*)d_in[9];
    const float* se_w1 = (const float*)d_in[10]; const float* se_b1 = (const float*)d_in[11];
    const float* se_w2 = (const float*)d_in[12]; const float* se_b2 = (const float*)d_in[13];
    const float* oe_w1 = (const float*)d_in[14]; const float* oe_b1 = (const float*)d_in[15];
    const float* oe_w2 = (const float*)d_in[16]; const float* oe_b2 = (const float*)d_in[17];
    const float* te_w1 = (const float*)d_in[18]; const float* te_b1 = (const float*)d_in[19];
    const float* te_w2 = (const float*)d_in[20]; const float* te_b2 = (const float*)d_in[21];
    const float* de_w1 = (const float*)d_in[22]; const float* de_b1 = (const float*)d_in[23];
    const float* de_w2 = (const float*)d_in[24]; const float* de_b2 = (const float*)d_in[25];
    const float* de_w3 = (const float*)d_in[26]; const float* de_b3 = (const float*)d_in[27];
    float* outp = (float*)d_out;

    const size_t WPACKB = (size_t)BATCH * GDIM * PROW;     // 402.7 MB packed int12
    const size_t AUXB = (size_t)BATCH * (GDIM * 3 + ZDIM + HDIM + 192) * 4
                      + (size_t)9 * BATCH * 512 * 4
                      + (size_t)9 * BATCH * GDIM * 4;
    const bool bf = ws_size >= WPACKB + AUXB;

    char* base = (char*)d_ws;
    float* scale_ws; float* g0_ws; float* z_ws;
    if (bf) {
        scale_ws = (float*)(base + WPACKB);
        g0_ws    = scale_ws + (size_t)BATCH * GDIM;
        z_ws     = g0_ws + (size_t)BATCH * GDIM;
    } else {
        scale_ws = nullptr;
        g0_ws    = nullptr;
        z_ws     = (float*)base;
    }
    float* g_ws    = z_ws + (size_t)BATCH * ZDIM;
    float* c_ws    = g_ws + (size_t)BATCH * GDIM;
    float* car_ws  = c_ws + (size_t)BATCH * HDIM;
    float* enc9_ws = car_ws + (size_t)BATCH * 192;
    float* E_ws    = enc9_ws + (size_t)9 * BATCH * 512;

    initk<<<dim3(BATCH), dim3(512), 0, stream>>>(prv, pq, pro, pqo, pc, tq, irp,
        se_w1, se_b1, se_w2, se_b2, oe_w1, oe_b1, oe_w2, oe_b2,
        te_w1, te_b1, te_w2, te_b2, z_ws, c_ws, car_ws);

    if (bf) {
        enc_past<<<dim3(BATCH, 9), dim3(512), 0, stream>>>(prv, pq, pro, pqo, pc,
            se_w1, se_b1, se_w2, se_b2, oe_w1, oe_b1, oe_w2, oe_b2, enc9_ws);
        matvec0_conv<<<dim3(BATCH * 32), dim3(256), 0, stream>>>(
            pw, z_ws, pb, (unsigned char*)d_ws, scale_ws, g_ws, g0_ws);
        epass<<<dim3(BATCH * 32), dim3(256), 0, stream>>>(
            (const unsigned char*)d_ws, enc9_ws, scale_ws, g0_ws, E_ws);
        for (int s = 0; s < NSTEPS; ++s) {
            if (s >= 1 && s < NPAST) {
                matvecH<<<dim3(BATCH * 32), dim3(256), 0, stream>>>(
                    (const unsigned char*)d_ws, z_ws, scale_ws,
                    E_ws + (size_t)(s - 1) * BATCH * GDIM, g_ws);
            } else if (s >= NPAST) {
                matvec12<<<dim3(BATCH * 32), dim3(256), 0, stream>>>(
                    (const unsigned char*)d_ws, z_ws, scale_ws, g0_ws, g_ws);
            }
            const int skip_enc = (s + 1 < NPAST) ? 1 : 0;
            stepk<<<dim3(BATCH), dim3(512), 0, stream>>>(prv, pq, pro, pqo, pc, trp, tq,
                se_w1, se_b1, se_w2, se_b2, oe_w1, oe_b1, oe_w2, oe_b2,
                de_w1, de_b1, de_w2, de_b2, de_w3, de_b3,
                outp, z_ws, g_ws, c_ws, car_ws, s, skip_enc);
        }
    } else {
        for (int s = 0; s < NSTEPS; ++s) {
            matvec_f32<<<dim3(BATCH * 32), dim3(256), 0, stream>>>(pw, z_ws, pb, g_ws);
            stepk<<<dim3(BATCH), dim3(512), 0, stream>>>(prv, pq, pro, pqo, pc, trp, tq,
                se_w1, se_b1, se_w2, se_b2, oe_w1, oe_b1, oe_w2, oe_b2,
                de_w1, de_b1, de_w2, de_b2, de_w3, de_b3,
                outp, z_ws, g_ws, c_ws, car_ws, s, 0);
        }
    }
}